// Round 13
// baseline (458.095 us; speedup 1.0000x reference)
//
#include <hip/hip_runtime.h>
#include <cfloat>
#include <cstdint>

// MahalanobisKnnModule v13: KS=32 conflict-free, ~6 waves/SIMD.
//   R11 failed KS=32 via (a) slot map q^(m&3): even rows hit slots {0,2}
//   only -> 4-way conflicts (bank base = (16(m&1)+4s)%32), (b) VGPR spill.
//   Fix: slot map sigma(m) = (m>>1)&3 (all 4 slots per row-parity class ->
//   exact 2-way = free), keep acc[4][2] (VGPR ~80).
//   cross: 128x64 tile, KS=32 phases, A dbuf 16K + B dbuf 8K + xp 1K =
//   25 KB -> 6 blocks/CU; grid 32x46=1472 (CHUNK 2176, 46*2176=100096
//   = exact 128-row tile cover); counted vmcnt(3).
//   msplit/xprod/finalize unchanged; prep/xsplit re-indexed for KS=32.

#define DD    256
#define NLAB  100
#define KNN   5
#define BCOLS 64
#define CHUNK 2176
#define NSRC  8

typedef float4 f4;
typedef __attribute__((ext_vector_type(8))) short bfrag;   // 8 bf16
typedef __attribute__((ext_vector_type(4))) float f32x4;

__device__ __forceinline__ void gload_lds16(const void* g, void* l) {
  __builtin_amdgcn_global_load_lds(
      (const __attribute__((address_space(1))) void*)g,
      (__attribute__((address_space(3))) void*)l, 16, 0, 0);
}

__device__ __forceinline__ uint32_t hi16(float v) {
  return ((__float_as_uint(v) + 0x8000u) & 0xffff0000u) >> 16;
}

__device__ __forceinline__ void split3(float v, uint32_t& h, uint32_t& m, uint32_t& l) {
  uint32_t b = __float_as_uint(v);
  uint32_t hb = (b + 0x8000u) & 0xffff0000u;
  float r1 = v - __uint_as_float(hb);
  uint32_t b1 = __float_as_uint(r1);
  uint32_t mb = (b1 + 0x8000u) & 0xffff0000u;
  float r2 = r1 - __uint_as_float(mb);
  uint32_t lb = (__float_as_uint(r2) + 0x8000u) & 0xffff0000u;
  h = hb >> 16; m = mb >> 16; l = lb >> 16;
}

__device__ __forceinline__ bool lex_lt(float v, int id, float rv, int rid) {
  return (v < rv) || (v == rv && id < rid);
}

__device__ __forceinline__ void ins5run(float (&bv)[KNN], int (&bi)[KNN], float v, int id) {
  if (v < bv[4]) {
    if (v < bv[3]) {
      bv[4] = bv[3]; bi[4] = bi[3];
      if (v < bv[2]) {
        bv[3] = bv[2]; bi[3] = bi[2];
        if (v < bv[1]) {
          bv[2] = bv[1]; bi[2] = bi[1];
          if (v < bv[0]) {
            bv[1] = bv[0]; bi[1] = bi[0]; bv[0] = v; bi[0] = id;
          } else { bv[1] = v; bi[1] = id; }
        } else { bv[2] = v; bi[2] = id; }
      } else { bv[3] = v; bi[3] = id; }
    } else { bv[4] = v; bi[4] = id; }
  }
}

__device__ __forceinline__ void ins5lex(float (&bv)[KNN], int (&bi)[KNN], float v, int id) {
  if (!lex_lt(v, id, bv[4], bi[4])) return;
  if (lex_lt(v, id, bv[3], bi[3])) {
    bv[4] = bv[3]; bi[4] = bi[3];
    if (lex_lt(v, id, bv[2], bi[2])) {
      bv[3] = bv[2]; bi[3] = bi[2];
      if (lex_lt(v, id, bv[1], bi[1])) {
        bv[2] = bv[1]; bi[2] = bi[1];
        if (lex_lt(v, id, bv[0], bi[0])) {
          bv[1] = bv[0]; bi[1] = bi[0]; bv[0] = v; bi[0] = id;
        } else { bv[1] = v; bi[1] = id; }
      } else { bv[2] = v; bi[2] = id; }
    } else { bv[3] = v; bi[3] = id; }
  } else { bv[4] = v; bi[4] = id; }
}

__device__ __forceinline__ void ins10(float (&bv)[10], int (&bi)[10], float v, int id) {
  if (!lex_lt(v, id, bv[9], bi[9])) return;
  bool placed = false;
#pragma unroll
  for (int s = 9; s >= 1; --s) {
    if (!placed) {
      if (lex_lt(v, id, bv[s - 1], bi[s - 1])) { bv[s] = bv[s - 1]; bi[s] = bi[s - 1]; }
      else { bv[s] = v; bi[s] = id; placed = true; }
    }
  }
  if (!placed) { bv[0] = v; bi[0] = id; }
}

// ---------- msplit: MT3 = 3-split of M, frag order for xprod ----------
__global__ __launch_bounds__(256)
void msplit_kernel(const float* __restrict__ M, uint4* __restrict__ MT3) {
  int id = blockIdx.x * 256 + threadIdx.x;
  int lane = id & 63;
  int nf = (id >> 6) & 15;
  int kit = id >> 10;
  int d = nf * 16 + (lane & 15);
  int kb = kit * 32 + (lane >> 4) * 8;
  uint32_t hw[4], mw[4], lw[4];
#pragma unroll
  for (int e = 0; e < 4; ++e) {
    uint32_t h0, m0, l0, h1, m1, l1;
    split3(M[(size_t)(kb + 2 * e) * DD + d], h0, m0, l0);
    split3(M[(size_t)(kb + 2 * e + 1) * DD + d], h1, m1, l1);
    hw[e] = h0 | (h1 << 16); mw[e] = m0 | (m1 << 16); lw[e] = l0 | (l1 << 16);
  }
  size_t base = (size_t)(kit * 16 + nf) * 3 * 64;
  MT3[base + lane]       = make_uint4(hw[0], hw[1], hw[2], hw[3]);
  MT3[base + 64 + lane]  = make_uint4(mw[0], mw[1], mw[2], mw[3]);
  MT3[base + 128 + lane] = make_uint4(lw[0], lw[1], lw[2], lw[3]);
}

// ---------- xsplit: Xsp[tile128][kit32 0..7][512 slots] ----------
// slot s: row m = s>>2, qs = s&3, k-quad q = qs ^ ((m>>1)&3); holds hi bf16
// of X[row][kit32*32 + q*8 .. +7]. 64B per row; sigma=(m>>1)&3 -> 2-way free.
__global__ __launch_bounds__(256)
void xsplit_kernel(const float* __restrict__ X, uint4* __restrict__ Xsp,
                   int NT, int NT128) {
  int id = blockIdx.x * 256 + threadIdx.x;
  int tile = id >> 12;
  if (tile >= NT128) return;
  int rem = id & 4095;
  int kit32 = rem >> 9;
  int s = rem & 511;
  int m = s >> 2, qs = s & 3;
  int q = qs ^ ((m >> 1) & 3);
  int row = tile * 128 + m; if (row >= NT) row = NT - 1;
  const float* src = X + (size_t)row * DD + kit32 * 32 + q * 8;
  f4 v0 = *(const f4*)src;
  f4 v1 = *(const f4*)(src + 4);
  uint32_t h0 = hi16(v0.x) | (hi16(v0.y) << 16);
  uint32_t h1 = hi16(v0.z) | (hi16(v0.w) << 16);
  uint32_t h2 = hi16(v1.x) | (hi16(v1.y) << 16);
  uint32_t h3 = hi16(v1.z) | (hi16(v1.w) << 16);
  Xsp[id] = make_uint4(h0, h1, h2, h3);
}

// ---------- prep: ZTf32 + Z2h[ct64][kit32][cc*4 + (q^((cc>>1)&3))] ----------
__global__ __launch_bounds__(256)
void prep_kernel(const float* __restrict__ M, const float* __restrict__ Xe,
                 float* __restrict__ ZTf32, uint4* __restrict__ Z2h, int NEVAL) {
  __shared__ float xe_lds[64 * 257];
  const int t = threadIdx.x;
  const int j0 = blockIdx.x * 64;
  const int part = t >> 6;
  const int dbase = blockIdx.y * 64 + part * 16;
#pragma unroll
  for (int it = 0; it < 16; ++it) {
    int id = t + it * 256;
    int r = id >> 6, k4 = id & 63;
    f4 v = *(const f4*)(Xe + (size_t)(j0 + r) * DD + 4 * k4);
    float* p = &xe_lds[r * 257 + 4 * k4];
    p[0] = v.x; p[1] = v.y; p[2] = v.z; p[3] = v.w;
  }
  __syncthreads();
  const int j = t & 63;
  float acc[16];
#pragma unroll
  for (int dd = 0; dd < 16; ++dd) acc[dd] = 0.f;
  for (int k4 = 0; k4 < 64; ++k4) {
    const float* xp = &xe_lds[j * 257 + 4 * k4];
    float x0 = xp[0], x1 = xp[1], x2 = xp[2], x3 = xp[3];
#pragma unroll
    for (int dd = 0; dd < 16; ++dd) {
      f4 m = *(const f4*)(M + (size_t)(dbase + dd) * DD + 4 * k4);
      acc[dd] = fmaf(m.x, x0, fmaf(m.y, x1, fmaf(m.z, x2, fmaf(m.w, x3, acc[dd]))));
    }
  }
  const int jg = j0 + j;
#pragma unroll
  for (int dd = 0; dd < 16; ++dd)
    ZTf32[(size_t)(dbase + dd) * NEVAL + jg] = acc[dd];
  const int cc = jg & 63, ct2 = jg >> 6;
  const int kit32 = dbase >> 5;
  const int oqb = (dbase & 31) >> 3;       // 0 or 2
  size_t zbase = ((size_t)ct2 * 8 + kit32) * 256 + cc * 4;
#pragma unroll
  for (int u = 0; u < 2; ++u) {
    uint32_t hw[4];
#pragma unroll
    for (int e = 0; e < 4; ++e) {
      uint32_t a0 = hi16(-2.f * acc[u * 8 + 2 * e]);
      uint32_t a1 = hi16(-2.f * acc[u * 8 + 2 * e + 1]);
      hw[e] = a0 | (a1 << 16);
    }
    Z2h[zbase + ((oqb + u) ^ ((cc >> 1) & 3))] =
        make_uint4(hw[0], hw[1], hw[2], hw[3]);
  }
}

// ---------- xprod: 3-split MFMA GEMM + fused row-dot (unchanged) ----------
__global__ __launch_bounds__(256, 2)
void xprod_kernel(const float* __restrict__ X, const uint4* __restrict__ MT3,
                  float* __restrict__ Xprod, int NT) {
  __shared__ __align__(16) char pool[66560];
  short* A3 = (short*)pool;
  char*  B3 = pool + 12288;
  float* C  = (float*)pool;

  const int t = threadIdx.x;
  const int w = t >> 6, lane = t & 63;
  const int l15 = lane & 15, l4 = lane >> 4;
  const int row0 = blockIdx.x * 64;
  const int r = t >> 2, g = t & 3;
  int grow = row0 + r; if (grow >= NT) grow = NT - 1;
  const float* xrow = X + (size_t)grow * DD;

  f32x4 acc[16];
#pragma unroll
  for (int nf = 0; nf < 16; ++nf) { f32x4 z = {0.f, 0.f, 0.f, 0.f}; acc[nf] = z; }

  for (int kit = 0; kit < 8; ++kit) {
    f4 v0 = *(const f4*)(xrow + kit * 32 + g * 8);
    f4 v1 = *(const f4*)(xrow + kit * 32 + g * 8 + 4);
    uint32_t h[8], m[8], l[8];
    split3(v0.x, h[0], m[0], l[0]); split3(v0.y, h[1], m[1], l[1]);
    split3(v0.z, h[2], m[2], l[2]); split3(v0.w, h[3], m[3], l[3]);
    split3(v1.x, h[4], m[4], l[4]); split3(v1.y, h[5], m[5], l[5]);
    split3(v1.z, h[6], m[6], l[6]); split3(v1.w, h[7], m[7], l[7]);
    int slot = (r & 15) + 16 * g;
    int wb = r >> 4;
    *(uint4*)((char*)A3 + ((wb * 3 + 0) * 64 + slot) * 16) =
        make_uint4(h[0] | (h[1] << 16), h[2] | (h[3] << 16), h[4] | (h[5] << 16), h[6] | (h[7] << 16));
    *(uint4*)((char*)A3 + ((wb * 3 + 1) * 64 + slot) * 16) =
        make_uint4(m[0] | (m[1] << 16), m[2] | (m[3] << 16), m[4] | (m[5] << 16), m[6] | (m[7] << 16));
    *(uint4*)((char*)A3 + ((wb * 3 + 2) * 64 + slot) * 16) =
        make_uint4(l[0] | (l[1] << 16), l[2] | (l[3] << 16), l[4] | (l[5] << 16), l[6] | (l[7] << 16));
    const uint4* src = MT3 + (size_t)kit * 3072;
#pragma unroll
    for (int i = 0; i < 12; ++i) {
      int gs = (w * 12 + i) * 64;
      gload_lds16(src + gs + lane, B3 + (size_t)gs * 16);
    }
    __syncthreads();
    bfrag ah = *(const bfrag*)((const char*)A3 + ((w * 3 + 0) * 64 + lane) * 16);
    bfrag am = *(const bfrag*)((const char*)A3 + ((w * 3 + 1) * 64 + lane) * 16);
    bfrag al = *(const bfrag*)((const char*)A3 + ((w * 3 + 2) * 64 + lane) * 16);
#pragma unroll
    for (int nf = 0; nf < 16; ++nf) {
      bfrag bh = *(const bfrag*)(B3 + ((nf * 3 + 0) * 64 + lane) * 16);
      bfrag bm = *(const bfrag*)(B3 + ((nf * 3 + 1) * 64 + lane) * 16);
      bfrag bl = *(const bfrag*)(B3 + ((nf * 3 + 2) * 64 + lane) * 16);
      acc[nf] = __builtin_amdgcn_mfma_f32_16x16x32_bf16(ah, bh, acc[nf], 0, 0, 0);
      acc[nf] = __builtin_amdgcn_mfma_f32_16x16x32_bf16(ah, bm, acc[nf], 0, 0, 0);
      acc[nf] = __builtin_amdgcn_mfma_f32_16x16x32_bf16(am, bh, acc[nf], 0, 0, 0);
      acc[nf] = __builtin_amdgcn_mfma_f32_16x16x32_bf16(ah, bl, acc[nf], 0, 0, 0);
      acc[nf] = __builtin_amdgcn_mfma_f32_16x16x32_bf16(al, bh, acc[nf], 0, 0, 0);
      acc[nf] = __builtin_amdgcn_mfma_f32_16x16x32_bf16(am, bm, acc[nf], 0, 0, 0);
    }
    __syncthreads();
  }
#pragma unroll
  for (int nf = 0; nf < 16; ++nf)
#pragma unroll
    for (int reg = 0; reg < 4; ++reg)
      C[(size_t)(16 * w + l4 * 4 + reg) * 260 + nf * 16 + l15] = acc[nf][reg];
  __syncthreads();
  float part = 0.f;
#pragma unroll
  for (int j = 0; j < 16; ++j) {
    f4 xv = *(const f4*)(xrow + g * 64 + 4 * j);
    f4 cv = *(const f4*)&C[(size_t)r * 260 + g * 64 + 4 * j];
    part = fmaf(xv.x, cv.x, fmaf(xv.y, cv.y, fmaf(xv.z, cv.z, fmaf(xv.w, cv.w, part))));
  }
  part += __shfl_xor(part, 1);
  part += __shfl_xor(part, 2);
  if (g == 0 && row0 + r < NT) Xprod[row0 + r] = part;
}

// ------- cross v13: 128x64 tile, KS=32 phases, ~6 waves/SIMD, vmcnt(3) -------
__global__ __launch_bounds__(256, 4)
void cross_topk_kernel(const uint4* __restrict__ Xsp, const uint4* __restrict__ Z2h,
                       const float* __restrict__ Xprod,
                       float* __restrict__ cand_v, int* __restrict__ cand_i,
                       int NT, int NCH, int NT128) {
  __shared__ __align__(16) char Abuf[2][8192];   // [row128][64B, sigma-XOR]
  __shared__ __align__(16) char Bbuf[2][4096];   // [col64][64B, sigma-XOR]
  __shared__ __align__(16) float xp_lds[256];    // 2 rowpairs of Xprod

  const int t = threadIdx.x;
  const int w = t >> 6, lane = t & 63;
  const int l15 = lane & 15, l4 = lane >> 4;
  const int wr = (w & 1) * 64;         // wave row offset
  const int wc = (w >> 1) * 32;        // wave col offset
  // XCD-aware swizzle (nwg = 32*46 = 1472, %8==0)
  int n = blockIdx.y * gridDim.x + blockIdx.x;
  int nwg = gridDim.x * gridDim.y;
  int wg = n;
  if ((nwg & 7) == 0) wg = (n & 7) * (nwg >> 3) + (n >> 3);
  const int ct = wg % gridDim.x;
  const int ch = wg / gridDim.x;
  const int c0 = ct * BCOLS;
  const int row0 = ch * CHUNK;
  const int rows = min(CHUNK, NT - row0);
  const int nrp = (rows + 127) >> 7;
  const int G = nrp * 8;
  const int tile0 = ch * (CHUNK >> 7);

  float bv[2][KNN]; int bi[2][KNN];
#pragma unroll
  for (int nf = 0; nf < 2; ++nf)
#pragma unroll
    for (int s = 0; s < KNN; ++s) { bv[nf][s] = FLT_MAX; bi[nf][s] = 0x7fffffff; }

  f32x4 acc[4][2];
#pragma unroll
  for (int mf = 0; mf < 4; ++mf)
#pragma unroll
    for (int nf = 0; nf < 2; ++nf) { f32x4 z = {0.f, 0.f, 0.f, 0.f}; acc[mf][nf] = z; }

  auto stageA = [&](int gg) {          // one kit32 A tile (512 uint4)
    int tile = tile0 + (gg >> 3); if (tile >= NT128) tile = NT128 - 1;
    const uint4* src = Xsp + (((size_t)tile * 8 + (gg & 7)) << 9);
    char* dst = Abuf[gg & 1];
#pragma unroll
    for (int i = 0; i < 2; ++i) {
      int sb = (w * 2 + i) * 64;
      gload_lds16(src + sb + lane, dst + sb * 16);
    }
  };
  auto stageB = [&](int gg) {          // one kit32 B tile (256 uint4)
    const uint4* src = Z2h + ((size_t)ct * 8 + (gg & 7)) * 256;
    gload_lds16(src + w * 64 + lane, Bbuf[gg & 1] + (w * 64) * 16);
  };

  // prologue: A0/B0 staged, full drain, single barrier
  stageA(0); stageB(0);
  asm volatile("s_waitcnt vmcnt(0)" ::: "memory");
  __builtin_amdgcn_s_barrier();

  for (int rp = 0; rp < nrp; ++rp) {
#pragma unroll
    for (int kit = 0; kit < 8; ++kit) {
      const int g = rp * 8 + kit;
      if (g < G - 1) {
        stageA(g + 1); stageB(g + 1);
        if (kit == 0 && !(rp & 1)) {
          // xp slice for rowpairs rp, rp+1 (1KB); duplicate per wave ->
          // symmetric vmcnt accounting; drained well before kit==7 read.
          gload_lds16((const uint4*)(Xprod + row0 + rp * 128) + lane,
                      (char*)xp_lds);
        }
        asm volatile("s_waitcnt vmcnt(3)" ::: "memory");
      } else {
        asm volatile("s_waitcnt vmcnt(0)" ::: "memory");
      }
      __builtin_amdgcn_s_barrier();
      const char* Ab = Abuf[kit & 1];
      const char* Bb = Bbuf[kit & 1];
      bfrag ah[4], bh[2];
#pragma unroll
      for (int mf = 0; mf < 4; ++mf) {
        int m = wr + mf * 16 + l15;
        ah[mf] = *(const bfrag*)(Ab + m * 64 + ((l4 ^ ((m >> 1) & 3)) << 4));
      }
#pragma unroll
      for (int nf = 0; nf < 2; ++nf) {
        int cc = wc + nf * 16 + l15;
        bh[nf] = *(const bfrag*)(Bb + cc * 64 + ((l4 ^ ((cc >> 1) & 3)) << 4));
      }
      __builtin_amdgcn_s_setprio(1);
#pragma unroll
      for (int mf = 0; mf < 4; ++mf)
#pragma unroll
        for (int nf = 0; nf < 2; ++nf)
          acc[mf][nf] = __builtin_amdgcn_mfma_f32_16x16x32_bf16(
              ah[mf], bh[nf], acc[mf][nf], 0, 0, 0);
      __builtin_amdgcn_s_setprio(0);
      if (kit == 7) {
        const int trow0 = row0 + rp * 128;
        const bool full = (trow0 + 128 <= NT);
#pragma unroll
        for (int mf = 0; mf < 4; ++mf) {
          f4 xv = *(const f4*)&xp_lds[(rp & 1) * 128 + wr + mf * 16 + l4 * 4];
          const int rbase = trow0 + wr + mf * 16 + l4 * 4;
#pragma unroll
          for (int nf = 0; nf < 2; ++nf) {
            float v0 = xv.x + acc[mf][nf][0];
            float v1 = xv.y + acc[mf][nf][1];
            float v2 = xv.z + acc[mf][nf][2];
            float v3 = xv.w + acc[mf][nf][3];
            if (!full) {
              if (rbase + 0 >= NT) v0 = FLT_MAX;
              if (rbase + 1 >= NT) v1 = FLT_MAX;
              if (rbase + 2 >= NT) v2 = FLT_MAX;
              if (rbase + 3 >= NT) v3 = FLT_MAX;
            }
            float mn = fminf(fminf(v0, v1), fminf(v2, v3));
            if (mn < bv[nf][4]) {        // rare path: detailed insert
              ins5run(bv[nf], bi[nf], v0, rbase);
              ins5run(bv[nf], bi[nf], v1, rbase + 1);
              ins5run(bv[nf], bi[nf], v2, rbase + 2);
              ins5run(bv[nf], bi[nf], v3, rbase + 3);
            }
            f32x4 zz = {0.f, 0.f, 0.f, 0.f};
            acc[mf][nf] = zz;
          }
        }
      }
      __builtin_amdgcn_s_barrier();
    }
  }

  // write 8 partial lists per column, layout [col][ch][src][5]
#pragma unroll
  for (int nf = 0; nf < 2; ++nf) {
    int col = c0 + wc + nf * 16 + l15;
    size_t o = ((size_t)col * NCH + ch) * (NSRC * KNN) + ((w & 1) * 4 + l4) * KNN;
#pragma unroll
    for (int s = 0; s < KNN; ++s) { cand_v[o + s] = bv[nf][s]; cand_i[o + s] = bi[nf][s]; }
  }
}

// ------------- finalize: merge -> top-10 -> exact rescore -> top-5 -------------
__global__ __launch_bounds__(64)
void finalize_kernel(const float* __restrict__ cand_v, const int* __restrict__ cand_i,
                     const float* __restrict__ X, const float* __restrict__ ZTf32,
                     const float* __restrict__ Xprod, const int* __restrict__ y,
                     float* __restrict__ out, int NCH, int NEVAL, int NT) {
  __shared__ float ztl[DD];
  const int j = blockIdx.x;
  const int lane = threadIdx.x;
#pragma unroll
  for (int i = 0; i < 4; ++i) {
    int k = lane + 64 * i;
    ztl[k] = ZTf32[(size_t)k * NEVAL + j];
  }
  __syncthreads();

  float bv[10]; int bi[10];
#pragma unroll
  for (int s = 0; s < 10; ++s) { bv[s] = FLT_MAX; bi[s] = 0x7fffffff; }
  const int NC = NCH * NSRC * KNN;     // 1840, contiguous per column
  const float* cvj = cand_v + (size_t)j * NC;
  const int*   cij = cand_i + (size_t)j * NC;
  for (int p = lane; p < NC; p += 64)
    ins10(bv, bi, cvj[p], cij[p]);
#pragma unroll
  for (int st = 0; st < 6; ++st) {
    float pv[10]; int pi[10];
#pragma unroll
    for (int s = 0; s < 10; ++s) {
      pv[s] = __shfl_xor(bv[s], 1 << st);
      pi[s] = __shfl_xor(bi[s], 1 << st);
    }
#pragma unroll
    for (int s = 0; s < 10; ++s) ins10(bv, bi, pv[s], pi[s]);
  }
  float ex[10];
#pragma unroll
  for (int c = 0; c < 10; ++c) {
    int idx = bi[c];
    float part = 0.f;
#pragma unroll
    for (int i = 0; i < 4; ++i) {
      int k = lane + 64 * i;
      part = fmaf(X[(size_t)idx * DD + k], ztl[k], part);
    }
#pragma unroll
    for (int st = 0; st < 6; ++st) part += __shfl_xor(part, 1 << st);
    ex[c] = Xprod[idx] - 2.f * part;
  }
  float fv[KNN]; int fi[KNN];
#pragma unroll
  for (int s = 0; s < KNN; ++s) { fv[s] = FLT_MAX; fi[s] = 0x7fffffff; }
#pragma unroll
  for (int c = 0; c < 10; ++c) ins5lex(fv, fi, ex[c], bi[c]);
  int lb[KNN];
#pragma unroll
  for (int s = 0; s < KNN; ++s) lb[s] = y[fi[s]];
  for (int q = lane; q < NLAB; q += 64) {
    int cnt = (lb[0] == q) + (lb[1] == q) + (lb[2] == q) + (lb[3] == q) + (lb[4] == q);
    out[(size_t)j * NLAB + q] = (float)cnt - (float)q * 0.01f;
  }
}

extern "C" void kernel_launch(void* const* d_in, const int* in_sizes, int n_in,
                              void* d_out, int out_size, void* d_ws, size_t ws_size,
                              hipStream_t stream) {
  const float* X  = (const float*)d_in[0];
  const float* M  = (const float*)d_in[1];
  const float* Xe = (const float*)d_in[2];
  const int*   y  = (const int*)d_in[3];
  const int NT    = in_sizes[0] / DD;          // 100000
  const int NEVAL = in_sizes[2] / DD;          // 2048
  const int NCH   = (NT + CHUNK - 1) / CHUNK;  // 46
  const int NT64  = (NT + 63) / 64;
  const int NT128 = (NT + 127) / 128;          // 782

  char* ws = (char*)d_ws;
  uint4* Z2h    = (uint4*)ws;                               // 1 MB
  float* ZTf32  = (float*)(ws + (1 << 20));                 // 2 MB
  uint4* MT3    = (uint4*)(ws + (3 << 20));                 // 384 KB
  float* Xprod  = (float*)(ws + (3 << 20) + (448 << 10));   // NCH*CHUNK + pad
  float* cand_v = (float*)(ws + (4 << 20));                 // 15.1 MB
  int*   cand_i = (int*)(cand_v + (size_t)NEVAL * NCH * NSRC * KNN);
  uint4* Xsp    = (uint4*)(ws + (40ULL << 20));             // 51.2 MB
  float* out    = (float*)d_out;

  msplit_kernel<<<dim3(32), 256, 0, stream>>>(M, MT3);
  prep_kernel<<<dim3(NEVAL / 64, DD / 64), 256, 0, stream>>>(M, Xe, ZTf32, Z2h, NEVAL);
  xsplit_kernel<<<dim3(NT128 * 16), 256, 0, stream>>>(X, Xsp, NT, NT128);
  xprod_kernel<<<dim3(NT64), 256, 0, stream>>>(X, MT3, Xprod, NT);
  cross_topk_kernel<<<dim3(NEVAL / BCOLS, NCH), 256, 0, stream>>>(
      Xsp, Z2h, Xprod, cand_v, cand_i, NT, NCH, NT128);
  finalize_kernel<<<dim3(NEVAL), 64, 0, stream>>>(
      cand_v, cand_i, X, ZTf32, Xprod, y, out, NCH, NEVAL, NT);
}

// Round 14
// 356.950 us; speedup vs baseline: 1.2834x; 1.2834x over previous
//
#include <hip/hip_runtime.h>
#include <cfloat>
#include <cstdint>

// MahalanobisKnnModule v14: v12 cross (proven 232us) + cheap prep pipeline.
//   R13 lesson: KS=32 doubles barrier overhead without raising measured
//   occupancy -> v12's KS=64 @ 3 blocks/CU is the structure optimum.
//   Changes vs v12 (cross/prep/finalize byte-identical):
//   - xprod: 2-split MFMA (hh+hl+lh; missing ll ~1e-3 abs vs top-10 gaps ~5)
//     -> half the MFMA, 2/3 the B staging; ALSO writes Xsp hi-tiles inline
//     (it already loads+splits exactly those 8-float groups).
//   - xsplit kernel deleted (fused into xprod).
//   - msplit -> 2-split MT2.

#define DD    256
#define NLAB  100
#define KNN   5
#define BCOLS 64
#define CHUNK 4224
#define NSRC  8

typedef float4 f4;
typedef __attribute__((ext_vector_type(8))) short bfrag;   // 8 bf16
typedef __attribute__((ext_vector_type(4))) float f32x4;

__device__ __forceinline__ void gload_lds16(const void* g, void* l) {
  __builtin_amdgcn_global_load_lds(
      (const __attribute__((address_space(1))) void*)g,
      (__attribute__((address_space(3))) void*)l, 16, 0, 0);
}

__device__ __forceinline__ uint32_t hi16(float v) {
  return ((__float_as_uint(v) + 0x8000u) & 0xffff0000u) >> 16;
}

// 2-split: round-to-nearest hi, residual lo
__device__ __forceinline__ void split2(float v, uint32_t& h, uint32_t& l) {
  uint32_t b = __float_as_uint(v);
  uint32_t hb = (b + 0x8000u) & 0xffff0000u;
  float lf = v - __uint_as_float(hb);
  h = hb >> 16;
  l = __float_as_uint(lf) >> 16;
}

__device__ __forceinline__ bool lex_lt(float v, int id, float rv, int rid) {
  return (v < rv) || (v == rv && id < rid);
}

__device__ __forceinline__ void ins5run(float (&bv)[KNN], int (&bi)[KNN], float v, int id) {
  if (v < bv[4]) {
    if (v < bv[3]) {
      bv[4] = bv[3]; bi[4] = bi[3];
      if (v < bv[2]) {
        bv[3] = bv[2]; bi[3] = bi[2];
        if (v < bv[1]) {
          bv[2] = bv[1]; bi[2] = bi[1];
          if (v < bv[0]) {
            bv[1] = bv[0]; bi[1] = bi[0]; bv[0] = v; bi[0] = id;
          } else { bv[1] = v; bi[1] = id; }
        } else { bv[2] = v; bi[2] = id; }
      } else { bv[3] = v; bi[3] = id; }
    } else { bv[4] = v; bi[4] = id; }
  }
}

__device__ __forceinline__ void ins5lex(float (&bv)[KNN], int (&bi)[KNN], float v, int id) {
  if (!lex_lt(v, id, bv[4], bi[4])) return;
  if (lex_lt(v, id, bv[3], bi[3])) {
    bv[4] = bv[3]; bi[4] = bi[3];
    if (lex_lt(v, id, bv[2], bi[2])) {
      bv[3] = bv[2]; bi[3] = bi[2];
      if (lex_lt(v, id, bv[1], bi[1])) {
        bv[2] = bv[1]; bi[2] = bi[1];
        if (lex_lt(v, id, bv[0], bi[0])) {
          bv[1] = bv[0]; bi[1] = bi[0]; bv[0] = v; bi[0] = id;
        } else { bv[1] = v; bi[1] = id; }
      } else { bv[2] = v; bi[2] = id; }
    } else { bv[3] = v; bi[3] = id; }
  } else { bv[4] = v; bi[4] = id; }
}

__device__ __forceinline__ void ins10(float (&bv)[10], int (&bi)[10], float v, int id) {
  if (!lex_lt(v, id, bv[9], bi[9])) return;
  bool placed = false;
#pragma unroll
  for (int s = 9; s >= 1; --s) {
    if (!placed) {
      if (lex_lt(v, id, bv[s - 1], bi[s - 1])) { bv[s] = bv[s - 1]; bi[s] = bi[s - 1]; }
      else { bv[s] = v; bi[s] = id; placed = true; }
    }
  }
  if (!placed) { bv[0] = v; bi[0] = id; }
}

// ---------- msplit2: MT2 = 2-split of M, frag order for xprod ----------
__global__ __launch_bounds__(256)
void msplit_kernel(const float* __restrict__ M, uint4* __restrict__ MT2) {
  int id = blockIdx.x * 256 + threadIdx.x;   // [0, 8192)
  int lane = id & 63;
  int nf = (id >> 6) & 15;
  int kit = id >> 10;
  int d = nf * 16 + (lane & 15);
  int kb = kit * 32 + (lane >> 4) * 8;
  uint32_t hw[4], lw[4];
#pragma unroll
  for (int e = 0; e < 4; ++e) {
    uint32_t h0, l0, h1, l1;
    split2(M[(size_t)(kb + 2 * e) * DD + d], h0, l0);
    split2(M[(size_t)(kb + 2 * e + 1) * DD + d], h1, l1);
    hw[e] = h0 | (h1 << 16); lw[e] = l0 | (l1 << 16);
  }
  size_t base = (size_t)(kit * 16 + nf) * 2 * 64;
  MT2[base + lane]      = make_uint4(hw[0], hw[1], hw[2], hw[3]);
  MT2[base + 64 + lane] = make_uint4(lw[0], lw[1], lw[2], lw[3]);
}

// ---------- prep (v12): ZTf32 + Z2h[ct64][kit64][cc*8 + (jj^(cc&7))] ----------
__global__ __launch_bounds__(256)
void prep_kernel(const float* __restrict__ M, const float* __restrict__ Xe,
                 float* __restrict__ ZTf32, uint4* __restrict__ Z2h, int NEVAL) {
  __shared__ float xe_lds[64 * 257];
  const int t = threadIdx.x;
  const int j0 = blockIdx.x * 64;
  const int part = t >> 6;
  const int dbase = blockIdx.y * 64 + part * 16;
#pragma unroll
  for (int it = 0; it < 16; ++it) {
    int id = t + it * 256;
    int r = id >> 6, k4 = id & 63;
    f4 v = *(const f4*)(Xe + (size_t)(j0 + r) * DD + 4 * k4);
    float* p = &xe_lds[r * 257 + 4 * k4];
    p[0] = v.x; p[1] = v.y; p[2] = v.z; p[3] = v.w;
  }
  __syncthreads();
  const int j = t & 63;
  float acc[16];
#pragma unroll
  for (int dd = 0; dd < 16; ++dd) acc[dd] = 0.f;
  for (int k4 = 0; k4 < 64; ++k4) {
    const float* xp = &xe_lds[j * 257 + 4 * k4];
    float x0 = xp[0], x1 = xp[1], x2 = xp[2], x3 = xp[3];
#pragma unroll
    for (int dd = 0; dd < 16; ++dd) {
      f4 m = *(const f4*)(M + (size_t)(dbase + dd) * DD + 4 * k4);
      acc[dd] = fmaf(m.x, x0, fmaf(m.y, x1, fmaf(m.z, x2, fmaf(m.w, x3, acc[dd]))));
    }
  }
  const int jg = j0 + j;
#pragma unroll
  for (int dd = 0; dd < 16; ++dd)
    ZTf32[(size_t)(dbase + dd) * NEVAL + jg] = acc[dd];
  const int cc = jg & 63, ct2 = jg >> 6;
  const int kit64 = dbase >> 6;
  const int jb = (dbase & 63) >> 3;             // {0,2,4,6}
  size_t zbase = (size_t)ct2 * 2048 + kit64 * 512 + cc * 8;
#pragma unroll
  for (int u = 0; u < 2; ++u) {
    int jj = jb + u;
    uint32_t hw[4];
#pragma unroll
    for (int e = 0; e < 4; ++e) {
      uint32_t a0 = hi16(-2.f * acc[u * 8 + 2 * e]);
      uint32_t a1 = hi16(-2.f * acc[u * 8 + 2 * e + 1]);
      hw[e] = a0 | (a1 << 16);
    }
    Z2h[zbase + (jj ^ (cc & 7))] = make_uint4(hw[0], hw[1], hw[2], hw[3]);
  }
}

// ---- xprod v14: 2-split MFMA GEMM + fused row-dot + fused Xsp-hi write ----
__global__ __launch_bounds__(256, 2)
void xprod_kernel(const float* __restrict__ X, const uint4* __restrict__ MT2,
                  float* __restrict__ Xprod, uint4* __restrict__ Xsp, int NT) {
  __shared__ __align__(16) char pool[66560];
  short* A2 = (short*)pool;                  // [4 w][2 s][64 lanes] x 16B = 8 KB
  char*  B2 = pool + 8192;                   // [16 nf][2 s][64 lanes] x 16B = 32 KB
  float* C  = (float*)pool;                  // [64][260] f32 overlay (post-barrier)

  const int t = threadIdx.x;
  const int w = t >> 6, lane = t & 63;
  const int l15 = lane & 15, l4 = lane >> 4;
  const int row0 = blockIdx.x * 64;
  const int r = t >> 2, g = t & 3;
  const int rowid = row0 + r;                // unclamped (for Xsp slot)
  int grow = rowid; if (grow >= NT) grow = NT - 1;
  const float* xrow = X + (size_t)grow * DD;
  // Xsp slot geometry (v12 oct-XOR layout), row part constant over kit
  const int xm = rowid & 127, xtile = rowid >> 7;

  f32x4 acc[16];
#pragma unroll
  for (int nf = 0; nf < 16; ++nf) { f32x4 z = {0.f, 0.f, 0.f, 0.f}; acc[nf] = z; }

  for (int kit = 0; kit < 8; ++kit) {
    f4 v0 = *(const f4*)(xrow + kit * 32 + g * 8);
    f4 v1 = *(const f4*)(xrow + kit * 32 + g * 8 + 4);
    uint32_t h[8], l[8];
    split2(v0.x, h[0], l[0]); split2(v0.y, h[1], l[1]);
    split2(v0.z, h[2], l[2]); split2(v0.w, h[3], l[3]);
    split2(v1.x, h[4], l[4]); split2(v1.y, h[5], l[5]);
    split2(v1.z, h[6], l[6]); split2(v1.w, h[7], l[7]);
    uint4 hp = make_uint4(h[0] | (h[1] << 16), h[2] | (h[3] << 16),
                          h[4] | (h[5] << 16), h[6] | (h[7] << 16));
    // fused Xsp write: k-oct jj of kit64, oct-XOR slot
    {
      int jj = (kit & 1) * 4 + g;
      Xsp[(((size_t)xtile * 4 + (kit >> 1)) << 10) + xm * 8 + (jj ^ (xm & 7))] = hp;
    }
    int slot = (r & 15) + 16 * g;
    int wb = r >> 4;
    *(uint4*)((char*)A2 + ((wb * 2 + 0) * 64 + slot) * 16) = hp;
    *(uint4*)((char*)A2 + ((wb * 2 + 1) * 64 + slot) * 16) =
        make_uint4(l[0] | (l[1] << 16), l[2] | (l[3] << 16),
                   l[4] | (l[5] << 16), l[6] | (l[7] << 16));
    const uint4* src = MT2 + (size_t)kit * 2048;
#pragma unroll
    for (int i = 0; i < 8; ++i) {
      int gs = (w * 8 + i) * 64;
      gload_lds16(src + gs + lane, B2 + (size_t)gs * 16);
    }
    __syncthreads();
    bfrag ah = *(const bfrag*)((const char*)A2 + ((w * 2 + 0) * 64 + lane) * 16);
    bfrag al = *(const bfrag*)((const char*)A2 + ((w * 2 + 1) * 64 + lane) * 16);
#pragma unroll
    for (int nf = 0; nf < 16; ++nf) {
      bfrag bh = *(const bfrag*)(B2 + ((nf * 2 + 0) * 64 + lane) * 16);
      bfrag bl = *(const bfrag*)(B2 + ((nf * 2 + 1) * 64 + lane) * 16);
      acc[nf] = __builtin_amdgcn_mfma_f32_16x16x32_bf16(ah, bh, acc[nf], 0, 0, 0);
      acc[nf] = __builtin_amdgcn_mfma_f32_16x16x32_bf16(ah, bl, acc[nf], 0, 0, 0);
      acc[nf] = __builtin_amdgcn_mfma_f32_16x16x32_bf16(al, bh, acc[nf], 0, 0, 0);
    }
    __syncthreads();
  }
#pragma unroll
  for (int nf = 0; nf < 16; ++nf)
#pragma unroll
    for (int reg = 0; reg < 4; ++reg)
      C[(size_t)(16 * w + l4 * 4 + reg) * 260 + nf * 16 + l15] = acc[nf][reg];
  __syncthreads();
  float part = 0.f;
#pragma unroll
  for (int j = 0; j < 16; ++j) {
    f4 xv = *(const f4*)(xrow + g * 64 + 4 * j);
    f4 cv = *(const f4*)&C[(size_t)r * 260 + g * 64 + 4 * j];
    part = fmaf(xv.x, cv.x, fmaf(xv.y, cv.y, fmaf(xv.z, cv.z, fmaf(xv.w, cv.w, part))));
  }
  part += __shfl_xor(part, 1);
  part += __shfl_xor(part, 2);
  if (g == 0 && rowid < NT) Xprod[rowid] = part;
}

// ------- cross v12 (verbatim): 128x64 tile, 3 blocks/CU, vmcnt(3) -------
__global__ __launch_bounds__(256, 3)
void cross_topk_kernel(const uint4* __restrict__ Xsp, const uint4* __restrict__ Z2h,
                       const float* __restrict__ Xprod,
                       float* __restrict__ cand_v, int* __restrict__ cand_i,
                       int NT, int NCH, int NT128) {
  __shared__ __align__(16) char Abuf[2][16384];   // [row128][128B oct-XOR]
  __shared__ __align__(16) char Bbuf[2][8192];    // [col64][128B oct-XOR]
  __shared__ __align__(16) float xp_lds[256];     // 2 rowpairs of Xprod

  const int t = threadIdx.x;
  const int w = t >> 6, lane = t & 63;
  const int l15 = lane & 15, l4 = lane >> 4;
  const int wr = (w & 1) * 64;
  const int wc = (w >> 1) * 32;
  int n = blockIdx.y * gridDim.x + blockIdx.x;
  int nwg = gridDim.x * gridDim.y;
  int wg = n;
  if ((nwg & 7) == 0) wg = (n & 7) * (nwg >> 3) + (n >> 3);
  const int ct = wg % gridDim.x;
  const int ch = wg / gridDim.x;
  const int c0 = ct * BCOLS;
  const int row0 = ch * CHUNK;
  const int rows = min(CHUNK, NT - row0);
  const int nrp = (rows + 127) >> 7;
  const int G = nrp * 4;
  const int tile0 = ch * (CHUNK >> 7);

  float bv[2][KNN]; int bi[2][KNN];
#pragma unroll
  for (int nf = 0; nf < 2; ++nf)
#pragma unroll
    for (int s = 0; s < KNN; ++s) { bv[nf][s] = FLT_MAX; bi[nf][s] = 0x7fffffff; }

  f32x4 acc[4][2];
#pragma unroll
  for (int mf = 0; mf < 4; ++mf)
#pragma unroll
    for (int nf = 0; nf < 2; ++nf) { f32x4 z = {0.f, 0.f, 0.f, 0.f}; acc[mf][nf] = z; }

  auto stageA = [&](int gg) {
    int tile = tile0 + (gg >> 2); if (tile >= NT128) tile = NT128 - 1;
    const uint4* src = Xsp + (((size_t)tile * 4 + (gg & 3)) << 10);
    char* dst = Abuf[gg & 1];
#pragma unroll
    for (int i = 0; i < 4; ++i) {
      int sb = (w * 4 + i) * 64;
      gload_lds16(src + sb + lane, dst + sb * 16);
    }
  };
  auto stageB = [&](int gg) {
    const uint4* src = Z2h + (size_t)ct * 2048 + (gg & 3) * 512;
    char* dst = Bbuf[gg & 1];
#pragma unroll
    for (int i = 0; i < 2; ++i) {
      int sb = (w * 2 + i) * 64;
      gload_lds16(src + sb + lane, dst + sb * 16);
    }
  };

  stageA(0); stageB(0);
  asm volatile("s_waitcnt vmcnt(0)" ::: "memory");
  __builtin_amdgcn_s_barrier();

  for (int rp = 0; rp < nrp; ++rp) {
#pragma unroll
    for (int kit = 0; kit < 4; ++kit) {
      const int g = rp * 4 + kit;
      if (g < G - 1) {
        stageA(g + 1); stageB(g + 1);
        if (kit == 0 && !(rp & 1)) {
          gload_lds16((const uint4*)(Xprod + row0 + rp * 128) + lane,
                      (char*)xp_lds);
        }
        asm volatile("s_waitcnt vmcnt(3)" ::: "memory");
      } else {
        asm volatile("s_waitcnt vmcnt(0)" ::: "memory");
      }
      __builtin_amdgcn_s_barrier();
      const char* Ab = Abuf[kit & 1];
      const char* Bb = Bbuf[kit & 1];
      bfrag ah[4][2], bh[2][2];
#pragma unroll
      for (int mf = 0; mf < 4; ++mf) {
        int m = wr + mf * 16 + l15;
        const char* rb = Ab + m * 128;
#pragma unroll
        for (int ks = 0; ks < 2; ++ks)
          ah[mf][ks] = *(const bfrag*)(rb + (((ks * 4 + l4) ^ (m & 7)) << 4));
      }
#pragma unroll
      for (int nf = 0; nf < 2; ++nf) {
        int cc = wc + nf * 16 + l15;
        const char* rb = Bb + cc * 128;
#pragma unroll
        for (int ks = 0; ks < 2; ++ks)
          bh[nf][ks] = *(const bfrag*)(rb + (((ks * 4 + l4) ^ (cc & 7)) << 4));
      }
      __builtin_amdgcn_s_setprio(1);
#pragma unroll
      for (int ks = 0; ks < 2; ++ks)
#pragma unroll
        for (int mf = 0; mf < 4; ++mf)
#pragma unroll
          for (int nf = 0; nf < 2; ++nf)
            acc[mf][nf] = __builtin_amdgcn_mfma_f32_16x16x32_bf16(
                ah[mf][ks], bh[nf][ks], acc[mf][nf], 0, 0, 0);
      __builtin_amdgcn_s_setprio(0);
      if (kit == 3) {
        const int trow0 = row0 + rp * 128;
        const bool full = (trow0 + 128 <= NT);
#pragma unroll
        for (int mf = 0; mf < 4; ++mf) {
          f4 xv = *(const f4*)&xp_lds[(rp & 1) * 128 + wr + mf * 16 + l4 * 4];
          const int rbase = trow0 + wr + mf * 16 + l4 * 4;
#pragma unroll
          for (int nf = 0; nf < 2; ++nf) {
            float v0 = xv.x + acc[mf][nf][0];
            float v1 = xv.y + acc[mf][nf][1];
            float v2 = xv.z + acc[mf][nf][2];
            float v3 = xv.w + acc[mf][nf][3];
            if (!full) {
              if (rbase + 0 >= NT) v0 = FLT_MAX;
              if (rbase + 1 >= NT) v1 = FLT_MAX;
              if (rbase + 2 >= NT) v2 = FLT_MAX;
              if (rbase + 3 >= NT) v3 = FLT_MAX;
            }
            float mn = fminf(fminf(v0, v1), fminf(v2, v3));
            if (mn < bv[nf][4]) {
              ins5run(bv[nf], bi[nf], v0, rbase);
              ins5run(bv[nf], bi[nf], v1, rbase + 1);
              ins5run(bv[nf], bi[nf], v2, rbase + 2);
              ins5run(bv[nf], bi[nf], v3, rbase + 3);
            }
            f32x4 zz = {0.f, 0.f, 0.f, 0.f};
            acc[mf][nf] = zz;
          }
        }
      }
      __builtin_amdgcn_s_barrier();
    }
  }

#pragma unroll
  for (int nf = 0; nf < 2; ++nf) {
    int col = c0 + wc + nf * 16 + l15;
    size_t o = ((size_t)col * NCH + ch) * (NSRC * KNN) + ((w & 1) * 4 + l4) * KNN;
#pragma unroll
    for (int s = 0; s < KNN; ++s) { cand_v[o + s] = bv[nf][s]; cand_i[o + s] = bi[nf][s]; }
  }
}

// ------------- finalize: merge -> top-10 -> exact rescore -> top-5 -------------
__global__ __launch_bounds__(64)
void finalize_kernel(const float* __restrict__ cand_v, const int* __restrict__ cand_i,
                     const float* __restrict__ X, const float* __restrict__ ZTf32,
                     const float* __restrict__ Xprod, const int* __restrict__ y,
                     float* __restrict__ out, int NCH, int NEVAL, int NT) {
  __shared__ float ztl[DD];
  const int j = blockIdx.x;
  const int lane = threadIdx.x;
#pragma unroll
  for (int i = 0; i < 4; ++i) {
    int k = lane + 64 * i;
    ztl[k] = ZTf32[(size_t)k * NEVAL + j];
  }
  __syncthreads();

  float bv[10]; int bi[10];
#pragma unroll
  for (int s = 0; s < 10; ++s) { bv[s] = FLT_MAX; bi[s] = 0x7fffffff; }
  const int NC = NCH * NSRC * KNN;     // 960, contiguous per column
  const float* cvj = cand_v + (size_t)j * NC;
  const int*   cij = cand_i + (size_t)j * NC;
  for (int p = lane; p < NC; p += 64)
    ins10(bv, bi, cvj[p], cij[p]);
#pragma unroll
  for (int st = 0; st < 6; ++st) {
    float pv[10]; int pi[10];
#pragma unroll
    for (int s = 0; s < 10; ++s) {
      pv[s] = __shfl_xor(bv[s], 1 << st);
      pi[s] = __shfl_xor(bi[s], 1 << st);
    }
#pragma unroll
    for (int s = 0; s < 10; ++s) ins10(bv, bi, pv[s], pi[s]);
  }
  float ex[10];
#pragma unroll
  for (int c = 0; c < 10; ++c) {
    int idx = bi[c];
    float part = 0.f;
#pragma unroll
    for (int i = 0; i < 4; ++i) {
      int k = lane + 64 * i;
      part = fmaf(X[(size_t)idx * DD + k], ztl[k], part);
    }
#pragma unroll
    for (int st = 0; st < 6; ++st) part += __shfl_xor(part, 1 << st);
    ex[c] = Xprod[idx] - 2.f * part;
  }
  float fv[KNN]; int fi[KNN];
#pragma unroll
  for (int s = 0; s < KNN; ++s) { fv[s] = FLT_MAX; fi[s] = 0x7fffffff; }
#pragma unroll
  for (int c = 0; c < 10; ++c) ins5lex(fv, fi, ex[c], bi[c]);
  int lb[KNN];
#pragma unroll
  for (int s = 0; s < KNN; ++s) lb[s] = y[fi[s]];
  for (int q = lane; q < NLAB; q += 64) {
    int cnt = (lb[0] == q) + (lb[1] == q) + (lb[2] == q) + (lb[3] == q) + (lb[4] == q);
    out[(size_t)j * NLAB + q] = (float)cnt - (float)q * 0.01f;
  }
}

extern "C" void kernel_launch(void* const* d_in, const int* in_sizes, int n_in,
                              void* d_out, int out_size, void* d_ws, size_t ws_size,
                              hipStream_t stream) {
  const float* X  = (const float*)d_in[0];
  const float* M  = (const float*)d_in[1];
  const float* Xe = (const float*)d_in[2];
  const int*   y  = (const int*)d_in[3];
  const int NT    = in_sizes[0] / DD;          // 100000
  const int NEVAL = in_sizes[2] / DD;          // 2048
  const int NCH   = (NT + CHUNK - 1) / CHUNK;  // 24
  const int NT64  = (NT + 63) / 64;            // 1563
  const int NT128 = (NT + 127) / 128;          // 782

  char* ws = (char*)d_ws;
  uint4* Z2h    = (uint4*)ws;                               // 1 MB
  float* ZTf32  = (float*)(ws + (1 << 20));                 // 2 MB
  uint4* MT2    = (uint4*)(ws + (3 << 20));                 // 256 KB
  float* Xprod  = (float*)(ws + (3 << 20) + (448 << 10));   // NT f32 + pad
  float* cand_v = (float*)(ws + (4 << 20));                 // 7.9 MB
  int*   cand_i = (int*)(cand_v + (size_t)NEVAL * NCH * NSRC * KNN);
  uint4* Xsp    = (uint4*)(ws + (40ULL << 20));             // 51.2 MB
  float* out    = (float*)d_out;

  msplit_kernel<<<dim3(32), 256, 0, stream>>>(M, MT2);
  prep_kernel<<<dim3(NEVAL / 64, DD / 64), 256, 0, stream>>>(M, Xe, ZTf32, Z2h, NEVAL);
  xprod_kernel<<<dim3(NT64), 256, 0, stream>>>(X, MT2, Xprod, Xsp, NT);
  cross_topk_kernel<<<dim3(NEVAL / BCOLS, NCH), 256, 0, stream>>>(
      Xsp, Z2h, Xprod, cand_v, cand_i, NT, NCH, NT128);
  finalize_kernel<<<dim3(NEVAL), 64, 0, stream>>>(
      cand_v, cand_i, X, ZTf32, Xprod, y, out, NCH, NEVAL, NT);
}

// Round 15
// 356.145 us; speedup vs baseline: 1.2863x; 1.0023x over previous
//
#include <hip/hip_runtime.h>
#include <cfloat>
#include <cstdint>

// MahalanobisKnnModule v15: v14 + B-in-registers cross.
//   B is rp-invariant: a wave's 2 col-frags x 256k = 16 bfrags = 64 VGPR,
//   loaded ONCE from L2 before the K-loop (v6's idea, but sized to fit:
//   B 64 + acc 32 + ah 32 + lists/temps ~= 160 <= 170 @ 3 blocks/CU).
//   Main loop stages ONLY A (dbuf 32KB + xp 1KB = 33.8KB LDS), 8 ds_read
//   + 16 MFMA per phase, counted vmcnt(3). Everything else = v14.

#define DD    256
#define NLAB  100
#define KNN   5
#define BCOLS 64
#define CHUNK 4224
#define NSRC  8

typedef float4 f4;
typedef __attribute__((ext_vector_type(8))) short bfrag;   // 8 bf16
typedef __attribute__((ext_vector_type(4))) float f32x4;

__device__ __forceinline__ void gload_lds16(const void* g, void* l) {
  __builtin_amdgcn_global_load_lds(
      (const __attribute__((address_space(1))) void*)g,
      (__attribute__((address_space(3))) void*)l, 16, 0, 0);
}

__device__ __forceinline__ uint32_t hi16(float v) {
  return ((__float_as_uint(v) + 0x8000u) & 0xffff0000u) >> 16;
}

// 2-split: round-to-nearest hi, residual lo
__device__ __forceinline__ void split2(float v, uint32_t& h, uint32_t& l) {
  uint32_t b = __float_as_uint(v);
  uint32_t hb = (b + 0x8000u) & 0xffff0000u;
  float lf = v - __uint_as_float(hb);
  h = hb >> 16;
  l = __float_as_uint(lf) >> 16;
}

__device__ __forceinline__ bool lex_lt(float v, int id, float rv, int rid) {
  return (v < rv) || (v == rv && id < rid);
}

__device__ __forceinline__ void ins5run(float (&bv)[KNN], int (&bi)[KNN], float v, int id) {
  if (v < bv[4]) {
    if (v < bv[3]) {
      bv[4] = bv[3]; bi[4] = bi[3];
      if (v < bv[2]) {
        bv[3] = bv[2]; bi[3] = bi[2];
        if (v < bv[1]) {
          bv[2] = bv[1]; bi[2] = bi[1];
          if (v < bv[0]) {
            bv[1] = bv[0]; bi[1] = bi[0]; bv[0] = v; bi[0] = id;
          } else { bv[1] = v; bi[1] = id; }
        } else { bv[2] = v; bi[2] = id; }
      } else { bv[3] = v; bi[3] = id; }
    } else { bv[4] = v; bi[4] = id; }
  }
}

__device__ __forceinline__ void ins5lex(float (&bv)[KNN], int (&bi)[KNN], float v, int id) {
  if (!lex_lt(v, id, bv[4], bi[4])) return;
  if (lex_lt(v, id, bv[3], bi[3])) {
    bv[4] = bv[3]; bi[4] = bi[3];
    if (lex_lt(v, id, bv[2], bi[2])) {
      bv[3] = bv[2]; bi[3] = bi[2];
      if (lex_lt(v, id, bv[1], bi[1])) {
        bv[2] = bv[1]; bi[2] = bi[1];
        if (lex_lt(v, id, bv[0], bi[0])) {
          bv[1] = bv[0]; bi[1] = bi[0]; bv[0] = v; bi[0] = id;
        } else { bv[1] = v; bi[1] = id; }
      } else { bv[2] = v; bi[2] = id; }
    } else { bv[3] = v; bi[3] = id; }
  } else { bv[4] = v; bi[4] = id; }
}

__device__ __forceinline__ void ins10(float (&bv)[10], int (&bi)[10], float v, int id) {
  if (!lex_lt(v, id, bv[9], bi[9])) return;
  bool placed = false;
#pragma unroll
  for (int s = 9; s >= 1; --s) {
    if (!placed) {
      if (lex_lt(v, id, bv[s - 1], bi[s - 1])) { bv[s] = bv[s - 1]; bi[s] = bi[s - 1]; }
      else { bv[s] = v; bi[s] = id; placed = true; }
    }
  }
  if (!placed) { bv[0] = v; bi[0] = id; }
}

// ---------- msplit2: MT2 = 2-split of M, frag order for xprod ----------
__global__ __launch_bounds__(256)
void msplit_kernel(const float* __restrict__ M, uint4* __restrict__ MT2) {
  int id = blockIdx.x * 256 + threadIdx.x;   // [0, 8192)
  int lane = id & 63;
  int nf = (id >> 6) & 15;
  int kit = id >> 10;
  int d = nf * 16 + (lane & 15);
  int kb = kit * 32 + (lane >> 4) * 8;
  uint32_t hw[4], lw[4];
#pragma unroll
  for (int e = 0; e < 4; ++e) {
    uint32_t h0, l0, h1, l1;
    split2(M[(size_t)(kb + 2 * e) * DD + d], h0, l0);
    split2(M[(size_t)(kb + 2 * e + 1) * DD + d], h1, l1);
    hw[e] = h0 | (h1 << 16); lw[e] = l0 | (l1 << 16);
  }
  size_t base = (size_t)(kit * 16 + nf) * 2 * 64;
  MT2[base + lane]      = make_uint4(hw[0], hw[1], hw[2], hw[3]);
  MT2[base + 64 + lane] = make_uint4(lw[0], lw[1], lw[2], lw[3]);
}

// ---------- prep (v12): ZTf32 + Z2h[ct64][kit64][cc*8 + (jj^(cc&7))] ----------
__global__ __launch_bounds__(256)
void prep_kernel(const float* __restrict__ M, const float* __restrict__ Xe,
                 float* __restrict__ ZTf32, uint4* __restrict__ Z2h, int NEVAL) {
  __shared__ float xe_lds[64 * 257];
  const int t = threadIdx.x;
  const int j0 = blockIdx.x * 64;
  const int part = t >> 6;
  const int dbase = blockIdx.y * 64 + part * 16;
#pragma unroll
  for (int it = 0; it < 16; ++it) {
    int id = t + it * 256;
    int r = id >> 6, k4 = id & 63;
    f4 v = *(const f4*)(Xe + (size_t)(j0 + r) * DD + 4 * k4);
    float* p = &xe_lds[r * 257 + 4 * k4];
    p[0] = v.x; p[1] = v.y; p[2] = v.z; p[3] = v.w;
  }
  __syncthreads();
  const int j = t & 63;
  float acc[16];
#pragma unroll
  for (int dd = 0; dd < 16; ++dd) acc[dd] = 0.f;
  for (int k4 = 0; k4 < 64; ++k4) {
    const float* xp = &xe_lds[j * 257 + 4 * k4];
    float x0 = xp[0], x1 = xp[1], x2 = xp[2], x3 = xp[3];
#pragma unroll
    for (int dd = 0; dd < 16; ++dd) {
      f4 m = *(const f4*)(M + (size_t)(dbase + dd) * DD + 4 * k4);
      acc[dd] = fmaf(m.x, x0, fmaf(m.y, x1, fmaf(m.z, x2, fmaf(m.w, x3, acc[dd]))));
    }
  }
  const int jg = j0 + j;
#pragma unroll
  for (int dd = 0; dd < 16; ++dd)
    ZTf32[(size_t)(dbase + dd) * NEVAL + jg] = acc[dd];
  const int cc = jg & 63, ct2 = jg >> 6;
  const int kit64 = dbase >> 6;
  const int jb = (dbase & 63) >> 3;             // {0,2,4,6}
  size_t zbase = (size_t)ct2 * 2048 + kit64 * 512 + cc * 8;
#pragma unroll
  for (int u = 0; u < 2; ++u) {
    int jj = jb + u;
    uint32_t hw[4];
#pragma unroll
    for (int e = 0; e < 4; ++e) {
      uint32_t a0 = hi16(-2.f * acc[u * 8 + 2 * e]);
      uint32_t a1 = hi16(-2.f * acc[u * 8 + 2 * e + 1]);
      hw[e] = a0 | (a1 << 16);
    }
    Z2h[zbase + (jj ^ (cc & 7))] = make_uint4(hw[0], hw[1], hw[2], hw[3]);
  }
}

// ---- xprod (v14): 2-split MFMA GEMM + fused row-dot + fused Xsp-hi write ----
__global__ __launch_bounds__(256, 2)
void xprod_kernel(const float* __restrict__ X, const uint4* __restrict__ MT2,
                  float* __restrict__ Xprod, uint4* __restrict__ Xsp, int NT) {
  __shared__ __align__(16) char pool[66560];
  short* A2 = (short*)pool;
  char*  B2 = pool + 8192;
  float* C  = (float*)pool;

  const int t = threadIdx.x;
  const int w = t >> 6, lane = t & 63;
  const int l15 = lane & 15, l4 = lane >> 4;
  const int row0 = blockIdx.x * 64;
  const int r = t >> 2, g = t & 3;
  const int rowid = row0 + r;
  int grow = rowid; if (grow >= NT) grow = NT - 1;
  const float* xrow = X + (size_t)grow * DD;
  const int xm = rowid & 127, xtile = rowid >> 7;

  f32x4 acc[16];
#pragma unroll
  for (int nf = 0; nf < 16; ++nf) { f32x4 z = {0.f, 0.f, 0.f, 0.f}; acc[nf] = z; }

  for (int kit = 0; kit < 8; ++kit) {
    f4 v0 = *(const f4*)(xrow + kit * 32 + g * 8);
    f4 v1 = *(const f4*)(xrow + kit * 32 + g * 8 + 4);
    uint32_t h[8], l[8];
    split2(v0.x, h[0], l[0]); split2(v0.y, h[1], l[1]);
    split2(v0.z, h[2], l[2]); split2(v0.w, h[3], l[3]);
    split2(v1.x, h[4], l[4]); split2(v1.y, h[5], l[5]);
    split2(v1.z, h[6], l[6]); split2(v1.w, h[7], l[7]);
    uint4 hp = make_uint4(h[0] | (h[1] << 16), h[2] | (h[3] << 16),
                          h[4] | (h[5] << 16), h[6] | (h[7] << 16));
    {
      int jj = (kit & 1) * 4 + g;
      Xsp[(((size_t)xtile * 4 + (kit >> 1)) << 10) + xm * 8 + (jj ^ (xm & 7))] = hp;
    }
    int slot = (r & 15) + 16 * g;
    int wb = r >> 4;
    *(uint4*)((char*)A2 + ((wb * 2 + 0) * 64 + slot) * 16) = hp;
    *(uint4*)((char*)A2 + ((wb * 2 + 1) * 64 + slot) * 16) =
        make_uint4(l[0] | (l[1] << 16), l[2] | (l[3] << 16),
                   l[4] | (l[5] << 16), l[6] | (l[7] << 16));
    const uint4* src = MT2 + (size_t)kit * 2048;
#pragma unroll
    for (int i = 0; i < 8; ++i) {
      int gs = (w * 8 + i) * 64;
      gload_lds16(src + gs + lane, B2 + (size_t)gs * 16);
    }
    __syncthreads();
    bfrag ah = *(const bfrag*)((const char*)A2 + ((w * 2 + 0) * 64 + lane) * 16);
    bfrag al = *(const bfrag*)((const char*)A2 + ((w * 2 + 1) * 64 + lane) * 16);
#pragma unroll
    for (int nf = 0; nf < 16; ++nf) {
      bfrag bh = *(const bfrag*)(B2 + ((nf * 2 + 0) * 64 + lane) * 16);
      bfrag bl = *(const bfrag*)(B2 + ((nf * 2 + 1) * 64 + lane) * 16);
      acc[nf] = __builtin_amdgcn_mfma_f32_16x16x32_bf16(ah, bh, acc[nf], 0, 0, 0);
      acc[nf] = __builtin_amdgcn_mfma_f32_16x16x32_bf16(ah, bl, acc[nf], 0, 0, 0);
      acc[nf] = __builtin_amdgcn_mfma_f32_16x16x32_bf16(al, bh, acc[nf], 0, 0, 0);
    }
    __syncthreads();
  }
#pragma unroll
  for (int nf = 0; nf < 16; ++nf)
#pragma unroll
    for (int reg = 0; reg < 4; ++reg)
      C[(size_t)(16 * w + l4 * 4 + reg) * 260 + nf * 16 + l15] = acc[nf][reg];
  __syncthreads();
  float part = 0.f;
#pragma unroll
  for (int j = 0; j < 16; ++j) {
    f4 xv = *(const f4*)(xrow + g * 64 + 4 * j);
    f4 cv = *(const f4*)&C[(size_t)r * 260 + g * 64 + 4 * j];
    part = fmaf(xv.x, cv.x, fmaf(xv.y, cv.y, fmaf(xv.z, cv.z, fmaf(xv.w, cv.w, part))));
  }
  part += __shfl_xor(part, 1);
  part += __shfl_xor(part, 2);
  if (g == 0 && rowid < NT) Xprod[rowid] = part;
}

// ------- cross v15: B-in-regs (64 VGPR), A-only dbuf, vmcnt(3) -------
__global__ __launch_bounds__(256, 3)
void cross_topk_kernel(const uint4* __restrict__ Xsp, const uint4* __restrict__ Z2h,
                       const float* __restrict__ Xprod,
                       float* __restrict__ cand_v, int* __restrict__ cand_i,
                       int NT, int NCH, int NT128) {
  __shared__ __align__(16) char Abuf[2][16384];   // [row128][128B oct-XOR]
  __shared__ __align__(16) float xp_lds[256];     // 2 rowpairs of Xprod

  const int t = threadIdx.x;
  const int w = t >> 6, lane = t & 63;
  const int l15 = lane & 15, l4 = lane >> 4;
  const int wr = (w & 1) * 64;
  const int wc = (w >> 1) * 32;
  int n = blockIdx.y * gridDim.x + blockIdx.x;
  int nwg = gridDim.x * gridDim.y;
  int wg = n;
  if ((nwg & 7) == 0) wg = (n & 7) * (nwg >> 3) + (n >> 3);
  const int ct = wg % gridDim.x;
  const int ch = wg / gridDim.x;
  const int c0 = ct * BCOLS;
  const int row0 = ch * CHUNK;
  const int rows = min(CHUNK, NT - row0);
  const int nrp = (rows + 127) >> 7;
  const int G = nrp * 4;
  const int tile0 = ch * (CHUNK >> 7);

  // ---- B entirely in registers: 2 nf x 8 k32-slices = 16 bfrags = 64 VGPR.
  // Same values v12 staged to LDS: Z2h[ct*2048 + kit64*512 + cc*8 + (jj^(cc&7))],
  // slice s: kit64 = s>>1, jj = (s&1)*4 + l4.
  bfrag bg[2][8];
#pragma unroll
  for (int nf = 0; nf < 2; ++nf) {
    int cc = wc + nf * 16 + l15;
    const uint4* zb = Z2h + (size_t)ct * 2048 + cc * 8;
#pragma unroll
    for (int s = 0; s < 8; ++s)
      bg[nf][s] = *(const bfrag*)(zb + (s >> 1) * 512 + (((s & 1) * 4 + l4) ^ (cc & 7)));
  }

  float bv[2][KNN]; int bi[2][KNN];
#pragma unroll
  for (int nf = 0; nf < 2; ++nf)
#pragma unroll
    for (int s = 0; s < KNN; ++s) { bv[nf][s] = FLT_MAX; bi[nf][s] = 0x7fffffff; }

  f32x4 acc[4][2];
#pragma unroll
  for (int mf = 0; mf < 4; ++mf)
#pragma unroll
    for (int nf = 0; nf < 2; ++nf) { f32x4 z = {0.f, 0.f, 0.f, 0.f}; acc[mf][nf] = z; }

  auto stageA = [&](int gg) {
    int tile = tile0 + (gg >> 2); if (tile >= NT128) tile = NT128 - 1;
    const uint4* src = Xsp + (((size_t)tile * 4 + (gg & 3)) << 10);
    char* dst = Abuf[gg & 1];
#pragma unroll
    for (int i = 0; i < 4; ++i) {
      int sb = (w * 4 + i) * 64;
      gload_lds16(src + sb + lane, dst + sb * 16);
    }
  };

  // prologue: A0 staged (B reg loads drain here too), single barrier
  stageA(0);
  asm volatile("s_waitcnt vmcnt(0)" ::: "memory");
  __builtin_amdgcn_s_barrier();

  for (int rp = 0; rp < nrp; ++rp) {
#pragma unroll
    for (int kit = 0; kit < 4; ++kit) {
      const int g = rp * 4 + kit;
      if (g < G - 1) {
        stageA(g + 1);
        if (kit == 0 && !(rp & 1)) {
          gload_lds16((const uint4*)(Xprod + row0 + rp * 128) + lane,
                      (char*)xp_lds);
        }
        asm volatile("s_waitcnt vmcnt(3)" ::: "memory");
      } else {
        asm volatile("s_waitcnt vmcnt(0)" ::: "memory");
      }
      __builtin_amdgcn_s_barrier();
      const char* Ab = Abuf[kit & 1];
      bfrag ah[4][2];
#pragma unroll
      for (int mf = 0; mf < 4; ++mf) {
        int m = wr + mf * 16 + l15;
        const char* rb = Ab + m * 128;
#pragma unroll
        for (int ks = 0; ks < 2; ++ks)
          ah[mf][ks] = *(const bfrag*)(rb + (((ks * 4 + l4) ^ (m & 7)) << 4));
      }
      __builtin_amdgcn_s_setprio(1);
#pragma unroll
      for (int ks = 0; ks < 2; ++ks)
#pragma unroll
        for (int mf = 0; mf < 4; ++mf)
#pragma unroll
          for (int nf = 0; nf < 2; ++nf)
            acc[mf][nf] = __builtin_amdgcn_mfma_f32_16x16x32_bf16(
                ah[mf][ks], bg[nf][kit * 2 + ks], acc[mf][nf], 0, 0, 0);
      __builtin_amdgcn_s_setprio(0);
      if (kit == 3) {
        const int trow0 = row0 + rp * 128;
        const bool full = (trow0 + 128 <= NT);
#pragma unroll
        for (int mf = 0; mf < 4; ++mf) {
          f4 xv = *(const f4*)&xp_lds[(rp & 1) * 128 + wr + mf * 16 + l4 * 4];
          const int rbase = trow0 + wr + mf * 16 + l4 * 4;
#pragma unroll
          for (int nf = 0; nf < 2; ++nf) {
            float v0 = xv.x + acc[mf][nf][0];
            float v1 = xv.y + acc[mf][nf][1];
            float v2 = xv.z + acc[mf][nf][2];
            float v3 = xv.w + acc[mf][nf][3];
            if (!full) {
              if (rbase + 0 >= NT) v0 = FLT_MAX;
              if (rbase + 1 >= NT) v1 = FLT_MAX;
              if (rbase + 2 >= NT) v2 = FLT_MAX;
              if (rbase + 3 >= NT) v3 = FLT_MAX;
            }
            float mn = fminf(fminf(v0, v1), fminf(v2, v3));
            if (mn < bv[nf][4]) {
              ins5run(bv[nf], bi[nf], v0, rbase);
              ins5run(bv[nf], bi[nf], v1, rbase + 1);
              ins5run(bv[nf], bi[nf], v2, rbase + 2);
              ins5run(bv[nf], bi[nf], v3, rbase + 3);
            }
            f32x4 zz = {0.f, 0.f, 0.f, 0.f};
            acc[mf][nf] = zz;
          }
        }
      }
      __builtin_amdgcn_s_barrier();
    }
  }

#pragma unroll
  for (int nf = 0; nf < 2; ++nf) {
    int col = c0 + wc + nf * 16 + l15;
    size_t o = ((size_t)col * NCH + ch) * (NSRC * KNN) + ((w & 1) * 4 + l4) * KNN;
#pragma unroll
    for (int s = 0; s < KNN; ++s) { cand_v[o + s] = bv[nf][s]; cand_i[o + s] = bi[nf][s]; }
  }
}

// ------------- finalize: merge -> top-10 -> exact rescore -> top-5 -------------
__global__ __launch_bounds__(64)
void finalize_kernel(const float* __restrict__ cand_v, const int* __restrict__ cand_i,
                     const float* __restrict__ X, const float* __restrict__ ZTf32,
                     const float* __restrict__ Xprod, const int* __restrict__ y,
                     float* __restrict__ out, int NCH, int NEVAL, int NT) {
  __shared__ float ztl[DD];
  const int j = blockIdx.x;
  const int lane = threadIdx.x;
#pragma unroll
  for (int i = 0; i < 4; ++i) {
    int k = lane + 64 * i;
    ztl[k] = ZTf32[(size_t)k * NEVAL + j];
  }
  __syncthreads();

  float bv[10]; int bi[10];
#pragma unroll
  for (int s = 0; s < 10; ++s) { bv[s] = FLT_MAX; bi[s] = 0x7fffffff; }
  const int NC = NCH * NSRC * KNN;     // 960, contiguous per column
  const float* cvj = cand_v + (size_t)j * NC;
  const int*   cij = cand_i + (size_t)j * NC;
  for (int p = lane; p < NC; p += 64)
    ins10(bv, bi, cvj[p], cij[p]);
#pragma unroll
  for (int st = 0; st < 6; ++st) {
    float pv[10]; int pi[10];
#pragma unroll
    for (int s = 0; s < 10; ++s) {
      pv[s] = __shfl_xor(bv[s], 1 << st);
      pi[s] = __shfl_xor(bi[s], 1 << st);
    }
#pragma unroll
    for (int s = 0; s < 10; ++s) ins10(bv, bi, pv[s], pi[s]);
  }
  float ex[10];
#pragma unroll
  for (int c = 0; c < 10; ++c) {
    int idx = bi[c];
    float part = 0.f;
#pragma unroll
    for (int i = 0; i < 4; ++i) {
      int k = lane + 64 * i;
      part = fmaf(X[(size_t)idx * DD + k], ztl[k], part);
    }
#pragma unroll
    for (int st = 0; st < 6; ++st) part += __shfl_xor(part, 1 << st);
    ex[c] = Xprod[idx] - 2.f * part;
  }
  float fv[KNN]; int fi[KNN];
#pragma unroll
  for (int s = 0; s < KNN; ++s) { fv[s] = FLT_MAX; fi[s] = 0x7fffffff; }
#pragma unroll
  for (int c = 0; c < 10; ++c) ins5lex(fv, fi, ex[c], bi[c]);
  int lb[KNN];
#pragma unroll
  for (int s = 0; s < KNN; ++s) lb[s] = y[fi[s]];
  for (int q = lane; q < NLAB; q += 64) {
    int cnt = (lb[0] == q) + (lb[1] == q) + (lb[2] == q) + (lb[3] == q) + (lb[4] == q);
    out[(size_t)j * NLAB + q] = (float)cnt - (float)q * 0.01f;
  }
}

extern "C" void kernel_launch(void* const* d_in, const int* in_sizes, int n_in,
                              void* d_out, int out_size, void* d_ws, size_t ws_size,
                              hipStream_t stream) {
  const float* X  = (const float*)d_in[0];
  const float* M  = (const float*)d_in[1];
  const float* Xe = (const float*)d_in[2];
  const int*   y  = (const int*)d_in[3];
  const int NT    = in_sizes[0] / DD;          // 100000
  const int NEVAL = in_sizes[2] / DD;          // 2048
  const int NCH   = (NT + CHUNK - 1) / CHUNK;  // 24
  const int NT64  = (NT + 63) / 64;            // 1563
  const int NT128 = (NT + 127) / 128;          // 782

  char* ws = (char*)d_ws;
  uint4* Z2h    = (uint4*)ws;                               // 1 MB
  float* ZTf32  = (float*)(ws + (1 << 20));                 // 2 MB
  uint4* MT2    = (uint4*)(ws + (3 << 20));                 // 256 KB
  float* Xprod  = (float*)(ws + (3 << 20) + (448 << 10));   // NT f32 + pad
  float* cand_v = (float*)(ws + (4 << 20));                 // 7.9 MB
  int*   cand_i = (int*)(cand_v + (size_t)NEVAL * NCH * NSRC * KNN);
  uint4* Xsp    = (uint4*)(ws + (40ULL << 20));             // 51.2 MB
  float* out    = (float*)d_out;

  msplit_kernel<<<dim3(32), 256, 0, stream>>>(M, MT2);
  prep_kernel<<<dim3(NEVAL / 64, DD / 64), 256, 0, stream>>>(M, Xe, ZTf32, Z2h, NEVAL);
  xprod_kernel<<<dim3(NT64), 256, 0, stream>>>(X, MT2, Xprod, Xsp, NT);
  cross_topk_kernel<<<dim3(NEVAL / BCOLS, NCH), 256, 0, stream>>>(
      Xsp, Z2h, Xprod, cand_v, cand_i, NT, NCH, NT128);
  finalize_kernel<<<dim3(NEVAL), 64, 0, stream>>>(
      cand_v, cand_i, X, ZTf32, Xprod, y, out, NCH, NEVAL, NT);
}

// Round 16
// 351.701 us; speedup vs baseline: 1.3025x; 1.0126x over previous
//
#include <hip/hip_runtime.h>
#include <cfloat>
#include <cstdint>

// MahalanobisKnnModule v16: v15 + vmcnt off-by-one fix.
//   R15 null-result diagnosis: phase wall was a counted-wait bug, not pipe
//   work. Each phase issues 4 A-loads then waited vmcnt(3): queue =
//   [prev-phase 4, just-issued 4] -> wait-to-3 drains one JUST-ISSUED load
//   = a full memory round-trip stall every phase. Fix: vmcnt(4) (drain
//   exactly prev phase's loads), and issue the xp slice BEFORE stageA so
//   [prev4, xp, new4] -> vmcnt(4) drains prev4+xp, never new4.
//   Everything else identical to v15 (ref-verified absmax 0).

#define DD    256
#define NLAB  100
#define KNN   5
#define BCOLS 64
#define CHUNK 4224
#define NSRC  8

typedef float4 f4;
typedef __attribute__((ext_vector_type(8))) short bfrag;   // 8 bf16
typedef __attribute__((ext_vector_type(4))) float f32x4;

__device__ __forceinline__ void gload_lds16(const void* g, void* l) {
  __builtin_amdgcn_global_load_lds(
      (const __attribute__((address_space(1))) void*)g,
      (__attribute__((address_space(3))) void*)l, 16, 0, 0);
}

__device__ __forceinline__ uint32_t hi16(float v) {
  return ((__float_as_uint(v) + 0x8000u) & 0xffff0000u) >> 16;
}

// 2-split: round-to-nearest hi, residual lo
__device__ __forceinline__ void split2(float v, uint32_t& h, uint32_t& l) {
  uint32_t b = __float_as_uint(v);
  uint32_t hb = (b + 0x8000u) & 0xffff0000u;
  float lf = v - __uint_as_float(hb);
  h = hb >> 16;
  l = __float_as_uint(lf) >> 16;
}

__device__ __forceinline__ bool lex_lt(float v, int id, float rv, int rid) {
  return (v < rv) || (v == rv && id < rid);
}

__device__ __forceinline__ void ins5run(float (&bv)[KNN], int (&bi)[KNN], float v, int id) {
  if (v < bv[4]) {
    if (v < bv[3]) {
      bv[4] = bv[3]; bi[4] = bi[3];
      if (v < bv[2]) {
        bv[3] = bv[2]; bi[3] = bi[2];
        if (v < bv[1]) {
          bv[2] = bv[1]; bi[2] = bi[1];
          if (v < bv[0]) {
            bv[1] = bv[0]; bi[1] = bi[0]; bv[0] = v; bi[0] = id;
          } else { bv[1] = v; bi[1] = id; }
        } else { bv[2] = v; bi[2] = id; }
      } else { bv[3] = v; bi[3] = id; }
    } else { bv[4] = v; bi[4] = id; }
  }
}

__device__ __forceinline__ void ins5lex(float (&bv)[KNN], int (&bi)[KNN], float v, int id) {
  if (!lex_lt(v, id, bv[4], bi[4])) return;
  if (lex_lt(v, id, bv[3], bi[3])) {
    bv[4] = bv[3]; bi[4] = bi[3];
    if (lex_lt(v, id, bv[2], bi[2])) {
      bv[3] = bv[2]; bi[3] = bi[2];
      if (lex_lt(v, id, bv[1], bi[1])) {
        bv[2] = bv[1]; bi[2] = bi[1];
        if (lex_lt(v, id, bv[0], bi[0])) {
          bv[1] = bv[0]; bi[1] = bi[0]; bv[0] = v; bi[0] = id;
        } else { bv[1] = v; bi[1] = id; }
      } else { bv[2] = v; bi[2] = id; }
    } else { bv[3] = v; bi[3] = id; }
  } else { bv[4] = v; bi[4] = id; }
}

__device__ __forceinline__ void ins10(float (&bv)[10], int (&bi)[10], float v, int id) {
  if (!lex_lt(v, id, bv[9], bi[9])) return;
  bool placed = false;
#pragma unroll
  for (int s = 9; s >= 1; --s) {
    if (!placed) {
      if (lex_lt(v, id, bv[s - 1], bi[s - 1])) { bv[s] = bv[s - 1]; bi[s] = bi[s - 1]; }
      else { bv[s] = v; bi[s] = id; placed = true; }
    }
  }
  if (!placed) { bv[0] = v; bi[0] = id; }
}

// ---------- msplit2: MT2 = 2-split of M, frag order for xprod ----------
__global__ __launch_bounds__(256)
void msplit_kernel(const float* __restrict__ M, uint4* __restrict__ MT2) {
  int id = blockIdx.x * 256 + threadIdx.x;   // [0, 8192)
  int lane = id & 63;
  int nf = (id >> 6) & 15;
  int kit = id >> 10;
  int d = nf * 16 + (lane & 15);
  int kb = kit * 32 + (lane >> 4) * 8;
  uint32_t hw[4], lw[4];
#pragma unroll
  for (int e = 0; e < 4; ++e) {
    uint32_t h0, l0, h1, l1;
    split2(M[(size_t)(kb + 2 * e) * DD + d], h0, l0);
    split2(M[(size_t)(kb + 2 * e + 1) * DD + d], h1, l1);
    hw[e] = h0 | (h1 << 16); lw[e] = l0 | (l1 << 16);
  }
  size_t base = (size_t)(kit * 16 + nf) * 2 * 64;
  MT2[base + lane]      = make_uint4(hw[0], hw[1], hw[2], hw[3]);
  MT2[base + 64 + lane] = make_uint4(lw[0], lw[1], lw[2], lw[3]);
}

// ---------- prep (v12): ZTf32 + Z2h[ct64][kit64][cc*8 + (jj^(cc&7))] ----------
__global__ __launch_bounds__(256)
void prep_kernel(const float* __restrict__ M, const float* __restrict__ Xe,
                 float* __restrict__ ZTf32, uint4* __restrict__ Z2h, int NEVAL) {
  __shared__ float xe_lds[64 * 257];
  const int t = threadIdx.x;
  const int j0 = blockIdx.x * 64;
  const int part = t >> 6;
  const int dbase = blockIdx.y * 64 + part * 16;
#pragma unroll
  for (int it = 0; it < 16; ++it) {
    int id = t + it * 256;
    int r = id >> 6, k4 = id & 63;
    f4 v = *(const f4*)(Xe + (size_t)(j0 + r) * DD + 4 * k4);
    float* p = &xe_lds[r * 257 + 4 * k4];
    p[0] = v.x; p[1] = v.y; p[2] = v.z; p[3] = v.w;
  }
  __syncthreads();
  const int j = t & 63;
  float acc[16];
#pragma unroll
  for (int dd = 0; dd < 16; ++dd) acc[dd] = 0.f;
  for (int k4 = 0; k4 < 64; ++k4) {
    const float* xp = &xe_lds[j * 257 + 4 * k4];
    float x0 = xp[0], x1 = xp[1], x2 = xp[2], x3 = xp[3];
#pragma unroll
    for (int dd = 0; dd < 16; ++dd) {
      f4 m = *(const f4*)(M + (size_t)(dbase + dd) * DD + 4 * k4);
      acc[dd] = fmaf(m.x, x0, fmaf(m.y, x1, fmaf(m.z, x2, fmaf(m.w, x3, acc[dd]))));
    }
  }
  const int jg = j0 + j;
#pragma unroll
  for (int dd = 0; dd < 16; ++dd)
    ZTf32[(size_t)(dbase + dd) * NEVAL + jg] = acc[dd];
  const int cc = jg & 63, ct2 = jg >> 6;
  const int kit64 = dbase >> 6;
  const int jb = (dbase & 63) >> 3;             // {0,2,4,6}
  size_t zbase = (size_t)ct2 * 2048 + kit64 * 512 + cc * 8;
#pragma unroll
  for (int u = 0; u < 2; ++u) {
    int jj = jb + u;
    uint32_t hw[4];
#pragma unroll
    for (int e = 0; e < 4; ++e) {
      uint32_t a0 = hi16(-2.f * acc[u * 8 + 2 * e]);
      uint32_t a1 = hi16(-2.f * acc[u * 8 + 2 * e + 1]);
      hw[e] = a0 | (a1 << 16);
    }
    Z2h[zbase + (jj ^ (cc & 7))] = make_uint4(hw[0], hw[1], hw[2], hw[3]);
  }
}

// ---- xprod (v14): 2-split MFMA GEMM + fused row-dot + fused Xsp-hi write ----
__global__ __launch_bounds__(256, 2)
void xprod_kernel(const float* __restrict__ X, const uint4* __restrict__ MT2,
                  float* __restrict__ Xprod, uint4* __restrict__ Xsp, int NT) {
  __shared__ __align__(16) char pool[66560];
  short* A2 = (short*)pool;
  char*  B2 = pool + 8192;
  float* C  = (float*)pool;

  const int t = threadIdx.x;
  const int w = t >> 6, lane = t & 63;
  const int l15 = lane & 15, l4 = lane >> 4;
  const int row0 = blockIdx.x * 64;
  const int r = t >> 2, g = t & 3;
  const int rowid = row0 + r;
  int grow = rowid; if (grow >= NT) grow = NT - 1;
  const float* xrow = X + (size_t)grow * DD;
  const int xm = rowid & 127, xtile = rowid >> 7;

  f32x4 acc[16];
#pragma unroll
  for (int nf = 0; nf < 16; ++nf) { f32x4 z = {0.f, 0.f, 0.f, 0.f}; acc[nf] = z; }

  for (int kit = 0; kit < 8; ++kit) {
    f4 v0 = *(const f4*)(xrow + kit * 32 + g * 8);
    f4 v1 = *(const f4*)(xrow + kit * 32 + g * 8 + 4);
    uint32_t h[8], l[8];
    split2(v0.x, h[0], l[0]); split2(v0.y, h[1], l[1]);
    split2(v0.z, h[2], l[2]); split2(v0.w, h[3], l[3]);
    split2(v1.x, h[4], l[4]); split2(v1.y, h[5], l[5]);
    split2(v1.z, h[6], l[6]); split2(v1.w, h[7], l[7]);
    uint4 hp = make_uint4(h[0] | (h[1] << 16), h[2] | (h[3] << 16),
                          h[4] | (h[5] << 16), h[6] | (h[7] << 16));
    {
      int jj = (kit & 1) * 4 + g;
      Xsp[(((size_t)xtile * 4 + (kit >> 1)) << 10) + xm * 8 + (jj ^ (xm & 7))] = hp;
    }
    int slot = (r & 15) + 16 * g;
    int wb = r >> 4;
    *(uint4*)((char*)A2 + ((wb * 2 + 0) * 64 + slot) * 16) = hp;
    *(uint4*)((char*)A2 + ((wb * 2 + 1) * 64 + slot) * 16) =
        make_uint4(l[0] | (l[1] << 16), l[2] | (l[3] << 16),
                   l[4] | (l[5] << 16), l[6] | (l[7] << 16));
    const uint4* src = MT2 + (size_t)kit * 2048;
#pragma unroll
    for (int i = 0; i < 8; ++i) {
      int gs = (w * 8 + i) * 64;
      gload_lds16(src + gs + lane, B2 + (size_t)gs * 16);
    }
    __syncthreads();
    bfrag ah = *(const bfrag*)((const char*)A2 + ((w * 2 + 0) * 64 + lane) * 16);
    bfrag al = *(const bfrag*)((const char*)A2 + ((w * 2 + 1) * 64 + lane) * 16);
#pragma unroll
    for (int nf = 0; nf < 16; ++nf) {
      bfrag bh = *(const bfrag*)(B2 + ((nf * 2 + 0) * 64 + lane) * 16);
      bfrag bl = *(const bfrag*)(B2 + ((nf * 2 + 1) * 64 + lane) * 16);
      acc[nf] = __builtin_amdgcn_mfma_f32_16x16x32_bf16(ah, bh, acc[nf], 0, 0, 0);
      acc[nf] = __builtin_amdgcn_mfma_f32_16x16x32_bf16(ah, bl, acc[nf], 0, 0, 0);
      acc[nf] = __builtin_amdgcn_mfma_f32_16x16x32_bf16(al, bh, acc[nf], 0, 0, 0);
    }
    __syncthreads();
  }
#pragma unroll
  for (int nf = 0; nf < 16; ++nf)
#pragma unroll
    for (int reg = 0; reg < 4; ++reg)
      C[(size_t)(16 * w + l4 * 4 + reg) * 260 + nf * 16 + l15] = acc[nf][reg];
  __syncthreads();
  float part = 0.f;
#pragma unroll
  for (int j = 0; j < 16; ++j) {
    f4 xv = *(const f4*)(xrow + g * 64 + 4 * j);
    f4 cv = *(const f4*)&C[(size_t)r * 260 + g * 64 + 4 * j];
    part = fmaf(xv.x, cv.x, fmaf(xv.y, cv.y, fmaf(xv.z, cv.z, fmaf(xv.w, cv.w, part))));
  }
  part += __shfl_xor(part, 1);
  part += __shfl_xor(part, 2);
  if (g == 0 && rowid < NT) Xprod[rowid] = part;
}

// ------- cross v16: B-in-regs, A-only dbuf, CORRECT vmcnt(4) -------
__global__ __launch_bounds__(256, 3)
void cross_topk_kernel(const uint4* __restrict__ Xsp, const uint4* __restrict__ Z2h,
                       const float* __restrict__ Xprod,
                       float* __restrict__ cand_v, int* __restrict__ cand_i,
                       int NT, int NCH, int NT128) {
  __shared__ __align__(16) char Abuf[2][16384];   // [row128][128B oct-XOR]
  __shared__ __align__(16) float xp_lds[256];     // 2 rowpairs of Xprod

  const int t = threadIdx.x;
  const int w = t >> 6, lane = t & 63;
  const int l15 = lane & 15, l4 = lane >> 4;
  const int wr = (w & 1) * 64;
  const int wc = (w >> 1) * 32;
  int n = blockIdx.y * gridDim.x + blockIdx.x;
  int nwg = gridDim.x * gridDim.y;
  int wg = n;
  if ((nwg & 7) == 0) wg = (n & 7) * (nwg >> 3) + (n >> 3);
  const int ct = wg % gridDim.x;
  const int ch = wg / gridDim.x;
  const int c0 = ct * BCOLS;
  const int row0 = ch * CHUNK;
  const int rows = min(CHUNK, NT - row0);
  const int nrp = (rows + 127) >> 7;
  const int G = nrp * 4;
  const int tile0 = ch * (CHUNK >> 7);

  // B entirely in registers: 2 nf x 8 k32-slices = 16 bfrags = 64 VGPR
  bfrag bg[2][8];
#pragma unroll
  for (int nf = 0; nf < 2; ++nf) {
    int cc = wc + nf * 16 + l15;
    const uint4* zb = Z2h + (size_t)ct * 2048 + cc * 8;
#pragma unroll
    for (int s = 0; s < 8; ++s)
      bg[nf][s] = *(const bfrag*)(zb + (s >> 1) * 512 + (((s & 1) * 4 + l4) ^ (cc & 7)));
  }

  float bv[2][KNN]; int bi[2][KNN];
#pragma unroll
  for (int nf = 0; nf < 2; ++nf)
#pragma unroll
    for (int s = 0; s < KNN; ++s) { bv[nf][s] = FLT_MAX; bi[nf][s] = 0x7fffffff; }

  f32x4 acc[4][2];
#pragma unroll
  for (int mf = 0; mf < 4; ++mf)
#pragma unroll
    for (int nf = 0; nf < 2; ++nf) { f32x4 z = {0.f, 0.f, 0.f, 0.f}; acc[mf][nf] = z; }

  auto stageA = [&](int gg) {
    int tile = tile0 + (gg >> 2); if (tile >= NT128) tile = NT128 - 1;
    const uint4* src = Xsp + (((size_t)tile * 4 + (gg & 3)) << 10);
    char* dst = Abuf[gg & 1];
#pragma unroll
    for (int i = 0; i < 4; ++i) {
      int sb = (w * 4 + i) * 64;
      gload_lds16(src + sb + lane, dst + sb * 16);
    }
  };

  // prologue: A0 staged (B reg loads drain here too), single barrier
  stageA(0);
  asm volatile("s_waitcnt vmcnt(0)" ::: "memory");
  __builtin_amdgcn_s_barrier();

  for (int rp = 0; rp < nrp; ++rp) {
#pragma unroll
    for (int kit = 0; kit < 4; ++kit) {
      const int g = rp * 4 + kit;
      if (g < G - 1) {
        // xp FIRST so vmcnt(4) drains [prev4, xp] and never the new 4
        if (kit == 0 && !(rp & 1)) {
          gload_lds16((const uint4*)(Xprod + row0 + rp * 128) + lane,
                      (char*)xp_lds);
        }
        stageA(g + 1);
        asm volatile("s_waitcnt vmcnt(4)" ::: "memory");
      } else {
        asm volatile("s_waitcnt vmcnt(0)" ::: "memory");
      }
      __builtin_amdgcn_s_barrier();
      const char* Ab = Abuf[kit & 1];
      bfrag ah[4][2];
#pragma unroll
      for (int mf = 0; mf < 4; ++mf) {
        int m = wr + mf * 16 + l15;
        const char* rb = Ab + m * 128;
#pragma unroll
        for (int ks = 0; ks < 2; ++ks)
          ah[mf][ks] = *(const bfrag*)(rb + (((ks * 4 + l4) ^ (m & 7)) << 4));
      }
      __builtin_amdgcn_s_setprio(1);
#pragma unroll
      for (int ks = 0; ks < 2; ++ks)
#pragma unroll
        for (int mf = 0; mf < 4; ++mf)
#pragma unroll
          for (int nf = 0; nf < 2; ++nf)
            acc[mf][nf] = __builtin_amdgcn_mfma_f32_16x16x32_bf16(
                ah[mf][ks], bg[nf][kit * 2 + ks], acc[mf][nf], 0, 0, 0);
      __builtin_amdgcn_s_setprio(0);
      if (kit == 3) {
        const int trow0 = row0 + rp * 128;
        const bool full = (trow0 + 128 <= NT);
#pragma unroll
        for (int mf = 0; mf < 4; ++mf) {
          f4 xv = *(const f4*)&xp_lds[(rp & 1) * 128 + wr + mf * 16 + l4 * 4];
          const int rbase = trow0 + wr + mf * 16 + l4 * 4;
#pragma unroll
          for (int nf = 0; nf < 2; ++nf) {
            float v0 = xv.x + acc[mf][nf][0];
            float v1 = xv.y + acc[mf][nf][1];
            float v2 = xv.z + acc[mf][nf][2];
            float v3 = xv.w + acc[mf][nf][3];
            if (!full) {
              if (rbase + 0 >= NT) v0 = FLT_MAX;
              if (rbase + 1 >= NT) v1 = FLT_MAX;
              if (rbase + 2 >= NT) v2 = FLT_MAX;
              if (rbase + 3 >= NT) v3 = FLT_MAX;
            }
            float mn = fminf(fminf(v0, v1), fminf(v2, v3));
            if (mn < bv[nf][4]) {
              ins5run(bv[nf], bi[nf], v0, rbase);
              ins5run(bv[nf], bi[nf], v1, rbase + 1);
              ins5run(bv[nf], bi[nf], v2, rbase + 2);
              ins5run(bv[nf], bi[nf], v3, rbase + 3);
            }
            f32x4 zz = {0.f, 0.f, 0.f, 0.f};
            acc[mf][nf] = zz;
          }
        }
      }
      __builtin_amdgcn_s_barrier();
    }
  }

#pragma unroll
  for (int nf = 0; nf < 2; ++nf) {
    int col = c0 + wc + nf * 16 + l15;
    size_t o = ((size_t)col * NCH + ch) * (NSRC * KNN) + ((w & 1) * 4 + l4) * KNN;
#pragma unroll
    for (int s = 0; s < KNN; ++s) { cand_v[o + s] = bv[nf][s]; cand_i[o + s] = bi[nf][s]; }
  }
}

// ------------- finalize: merge -> top-10 -> exact rescore -> top-5 -------------
__global__ __launch_bounds__(64)
void finalize_kernel(const float* __restrict__ cand_v, const int* __restrict__ cand_i,
                     const float* __restrict__ X, const float* __restrict__ ZTf32,
                     const float* __restrict__ Xprod, const int* __restrict__ y,
                     float* __restrict__ out, int NCH, int NEVAL, int NT) {
  __shared__ float ztl[DD];
  const int j = blockIdx.x;
  const int lane = threadIdx.x;
#pragma unroll
  for (int i = 0; i < 4; ++i) {
    int k = lane + 64 * i;
    ztl[k] = ZTf32[(size_t)k * NEVAL + j];
  }
  __syncthreads();

  float bv[10]; int bi[10];
#pragma unroll
  for (int s = 0; s < 10; ++s) { bv[s] = FLT_MAX; bi[s] = 0x7fffffff; }
  const int NC = NCH * NSRC * KNN;     // 960, contiguous per column
  const float* cvj = cand_v + (size_t)j * NC;
  const int*   cij = cand_i + (size_t)j * NC;
  for (int p = lane; p < NC; p += 64)
    ins10(bv, bi, cvj[p], cij[p]);
#pragma unroll
  for (int st = 0; st < 6; ++st) {
    float pv[10]; int pi[10];
#pragma unroll
    for (int s = 0; s < 10; ++s) {
      pv[s] = __shfl_xor(bv[s], 1 << st);
      pi[s] = __shfl_xor(bi[s], 1 << st);
    }
#pragma unroll
    for (int s = 0; s < 10; ++s) ins10(bv, bi, pv[s], pi[s]);
  }
  float ex[10];
#pragma unroll
  for (int c = 0; c < 10; ++c) {
    int idx = bi[c];
    float part = 0.f;
#pragma unroll
    for (int i = 0; i < 4; ++i) {
      int k = lane + 64 * i;
      part = fmaf(X[(size_t)idx * DD + k], ztl[k], part);
    }
#pragma unroll
    for (int st = 0; st < 6; ++st) part += __shfl_xor(part, 1 << st);
    ex[c] = Xprod[idx] - 2.f * part;
  }
  float fv[KNN]; int fi[KNN];
#pragma unroll
  for (int s = 0; s < KNN; ++s) { fv[s] = FLT_MAX; fi[s] = 0x7fffffff; }
#pragma unroll
  for (int c = 0; c < 10; ++c) ins5lex(fv, fi, ex[c], bi[c]);
  int lb[KNN];
#pragma unroll
  for (int s = 0; s < KNN; ++s) lb[s] = y[fi[s]];
  for (int q = lane; q < NLAB; q += 64) {
    int cnt = (lb[0] == q) + (lb[1] == q) + (lb[2] == q) + (lb[3] == q) + (lb[4] == q);
    out[(size_t)j * NLAB + q] = (float)cnt - (float)q * 0.01f;
  }
}

extern "C" void kernel_launch(void* const* d_in, const int* in_sizes, int n_in,
                              void* d_out, int out_size, void* d_ws, size_t ws_size,
                              hipStream_t stream) {
  const float* X  = (const float*)d_in[0];
  const float* M  = (const float*)d_in[1];
  const float* Xe = (const float*)d_in[2];
  const int*   y  = (const int*)d_in[3];
  const int NT    = in_sizes[0] / DD;          // 100000
  const int NEVAL = in_sizes[2] / DD;          // 2048
  const int NCH   = (NT + CHUNK - 1) / CHUNK;  // 24
  const int NT64  = (NT + 63) / 64;            // 1563
  const int NT128 = (NT + 127) / 128;          // 782

  char* ws = (char*)d_ws;
  uint4* Z2h    = (uint4*)ws;                               // 1 MB
  float* ZTf32  = (float*)(ws + (1 << 20));                 // 2 MB
  uint4* MT2    = (uint4*)(ws + (3 << 20));                 // 256 KB
  float* Xprod  = (float*)(ws + (3 << 20) + (448 << 10));   // NT f32 + pad
  float* cand_v = (float*)(ws + (4 << 20));                 // 7.9 MB
  int*   cand_i = (int*)(cand_v + (size_t)NEVAL * NCH * NSRC * KNN);
  uint4* Xsp    = (uint4*)(ws + (40ULL << 20));             // 51.2 MB
  float* out    = (float*)d_out;

  msplit_kernel<<<dim3(32), 256, 0, stream>>>(M, MT2);
  prep_kernel<<<dim3(NEVAL / 64, DD / 64), 256, 0, stream>>>(M, Xe, ZTf32, Z2h, NEVAL);
  xprod_kernel<<<dim3(NT64), 256, 0, stream>>>(X, MT2, Xprod, Xsp, NT);
  cross_topk_kernel<<<dim3(NEVAL / BCOLS, NCH), 256, 0, stream>>>(
      Xsp, Z2h, Xprod, cand_v, cand_i, NT, NCH, NT128);
  finalize_kernel<<<dim3(NEVAL), 64, 0, stream>>>(
      cand_v, cand_i, X, ZTf32, Xprod, y, out, NCH, NEVAL, NT);
}